// Round 6
// baseline (218.739 us; speedup 1.0000x reference)
//
#include <hip/hip_runtime.h>
#include <hip/hip_bf16.h>
#include <cmath>

typedef unsigned short u16;
typedef __attribute__((ext_vector_type(8))) short s8v;    // 8 x bf16 bits
typedef __attribute__((ext_vector_type(4))) float f4v;
typedef __attribute__((ext_vector_type(4))) unsigned short u16x4;

#define MFMA(a,b,c) __builtin_amdgcn_mfma_f32_16x16x32_bf16((a),(b),(c),0,0,0)

__device__ __forceinline__ float bf2f(u16 u) {
    union { float f; unsigned i; } x; x.i = ((unsigned)u) << 16; return x.f;
}
__device__ __forceinline__ u16 f2bf(float f) {
    union { float f; unsigned i; } x; x.f = f;
    unsigned r = x.i + 0x7FFFu + ((x.i >> 16) & 1u);
    return (u16)(r >> 16);
}
__device__ __forceinline__ unsigned cvtpk(float lo, float hi) {
    unsigned r;
    asm("v_cvt_pk_bf16_f32 %0, %1, %2" : "=v"(r) : "v"(lo), "v"(hi));
    return r;
}

// chunks-per-qblock and per-p-tile prefix (512-key chunks, block-causal)
__constant__ int CPER[8]  = {1,1,2,2,3,3,4,4};
__constant__ int POFF[17] = {0,1,2,3,4,6,8,10,12,15,18,21,24,28,32,36,40};

// ---------------------------------------------------------------------------
// Kernel 1: fused QKV projection (f32 in -> bf16 MFMA -> bf16 out).
// Q output PRESCALED by 0.125*log2(e). Q,K: [b][h][T][d]; V: VT [b][h][d][T].
// ---------------------------------------------------------------------------
__global__ __launch_bounds__(256)
void qkv_proj(const float* __restrict__ q, const float* __restrict__ kv,
              const float* __restrict__ Wq, const float* __restrict__ bq,
              const float* __restrict__ Wkv, const float* __restrict__ bkv,
              u16* __restrict__ QH, u16* __restrict__ KH, u16* __restrict__ VT)
{
    __shared__ u16 Al[128][40];
    __shared__ u16 Bl[128][40];

    const int bid = blockIdx.x;
    const int mt = bid / 12, nt = bid - mt * 12;
    const int m0 = mt << 7, n0 = nt << 7;

    const int tid  = threadIdx.x;
    const int lane = tid & 63;
    const int w    = tid >> 6;
    const int wr = (w >> 1) * 64, wc = (w & 1) * 64;
    const int cl = lane & 15, rl = lane >> 4;

    const int bb  = m0 >> 11;
    const int t0  = m0 & 2047;
    const int vv  = t0 >> 8;
    const int hw0 = t0 & 255;

    const float* Abase = ((nt < 4) ? q : kv) + (size_t)(vv * 4 + bb) * 131072 + hw0;

    const float* W; const float* bias; int NW, wn0, dn0; u16* dst;
    if (nt < 4)      { W = Wq;  bias = bq;  NW = 512;  wn0 = n0;       dn0 = n0;        dst = QH; }
    else if (nt < 8) { W = Wkv; bias = bkv; NW = 1024; wn0 = n0 - 512; dn0 = n0 - 512;  dst = KH; }
    else             { W = Wkv; bias = bkv; NW = 1024; wn0 = n0 - 512; dn0 = n0 - 1024; dst = VT; }

    const float oscale = (nt < 4) ? 0.18033688011f : 1.0f;  // 0.125*log2(e)

    f4v acc[4][4] = {};

    const int lk = tid >> 3;
    const int lg = (tid & 7) * 16;

    for (int k0 = 0; k0 < 512; k0 += 32) {
        {
            const float* g = Abase + (size_t)(k0 + lk) * 256 + lg;
            #pragma unroll
            for (int u = 0; u < 4; ++u) {
                f4v v = *reinterpret_cast<const f4v*>(g + u * 4);
                unsigned w0 = cvtpk(v[0], v[1]);
                unsigned w1 = cvtpk(v[2], v[3]);
                Al[lg + u * 4 + 0][lk] = (u16)w0;
                Al[lg + u * 4 + 1][lk] = (u16)(w0 >> 16);
                Al[lg + u * 4 + 2][lk] = (u16)w1;
                Al[lg + u * 4 + 3][lk] = (u16)(w1 >> 16);
            }
        }
        {
            const float* g = W + (size_t)(k0 + lk) * NW + wn0 + lg;
            #pragma unroll
            for (int u = 0; u < 4; ++u) {
                f4v v = *reinterpret_cast<const f4v*>(g + u * 4);
                unsigned w0 = cvtpk(v[0], v[1]);
                unsigned w1 = cvtpk(v[2], v[3]);
                Bl[lg + u * 4 + 0][lk] = (u16)w0;
                Bl[lg + u * 4 + 1][lk] = (u16)(w0 >> 16);
                Bl[lg + u * 4 + 2][lk] = (u16)w1;
                Bl[lg + u * 4 + 3][lk] = (u16)(w1 >> 16);
            }
        }
        __syncthreads();
        s8v af[4], bf[4];
        #pragma unroll
        for (int mi = 0; mi < 4; ++mi)
            af[mi] = *reinterpret_cast<const s8v*>(&Al[wr + mi * 16 + cl][rl * 8]);
        #pragma unroll
        for (int ni = 0; ni < 4; ++ni)
            bf[ni] = *reinterpret_cast<const s8v*>(&Bl[wc + ni * 16 + cl][rl * 8]);
        #pragma unroll
        for (int mi = 0; mi < 4; ++mi)
            #pragma unroll
            for (int ni = 0; ni < 4; ++ni)
                acc[mi][ni] = MFMA(af[mi], bf[ni], acc[mi][ni]);
        __syncthreads();
    }

    if (nt < 8) {
        #pragma unroll
        for (int ni = 0; ni < 4; ++ni) {
            const int nl   = wc + ni * 16 + cl;
            const float bv = bias[wn0 + nl];
            const int cout = dn0 + nl;
            const int hh = cout >> 6, dd = cout & 63;
            const size_t obase = ((size_t)(bb * 8 + hh) * 2048) * 64 + dd;
            #pragma unroll
            for (int mi = 0; mi < 4; ++mi)
                #pragma unroll
                for (int r = 0; r < 4; ++r) {
                    const int m = m0 + wr + mi * 16 + rl * 4 + r;
                    const int t = m & 2047;
                    dst[obase + (size_t)t * 64] = f2bf((acc[mi][ni][r] + bv) * oscale);
                }
        }
    } else {
        #pragma unroll
        for (int ni = 0; ni < 4; ++ni) {
            const int nl   = wc + ni * 16 + cl;
            const float bv = bias[wn0 + nl];
            const int cout = dn0 + nl;
            const int hh = cout >> 6, dd = cout & 63;
            const size_t obase = ((size_t)(bb * 8 + hh) * 64 + dd) * 2048;
            #pragma unroll
            for (int mi = 0; mi < 4; ++mi) {
                const int m = m0 + wr + mi * 16 + rl * 4;
                const int t = m & 2047;
                u16x4 pk;
                #pragma unroll
                for (int r = 0; r < 4; ++r) pk[r] = f2bf(acc[mi][ni][r] + bv);
                *reinterpret_cast<u16x4*>(dst + obase + t) = pk;
            }
        }
    }
}

// ---------------------------------------------------------------------------
// Kernel 2a: attention partials. WG = (bh, 128-row q-tile p, 512-key chunk c).
// K/V LDS tiles XOR-swizzled (T2, conflict-free ds_read_b128) and staged with
// issue-early/write-late (T14): tile kt+1's global loads issue before tile
// kt's compute, hiding L2/L3 latency under MFMA+softmax.
// ---------------------------------------------------------------------------
__global__ __launch_bounds__(256, 3)
void attn_part(const u16* __restrict__ QH, const u16* __restrict__ KH,
               const u16* __restrict__ VT,
               u16* __restrict__ Opart, float* __restrict__ ML)
{
    __shared__ __align__(16) u16 Kl[8192];   // [128 keys][64 d], byte^=( (key&7)<<4)
    __shared__ __align__(16) u16 Vl[8192];   // [64 d][128 keys], byte^=( (d&15)<<4)
    __shared__ u16 Pl[4][32][36];            // per-wave 32-key P slice

    const int wg = blockIdx.x;
    const int bh = wg & 31;
    const int s  = wg >> 5;               // 0..39 chunk slot within bh
    int p = 0;
    #pragma unroll
    for (int i = 0; i < 15; ++i) p += (s >= POFF[i + 1]) ? 1 : 0;
    const int c  = s - POFF[p];
    const int qb = p >> 1;
    const int kstart = c * 512;
    const int nk = min(512, (qb + 1) * 256 - kstart);
    const int nt128 = nk >> 7;            // 2 or 4 key tiles of 128

    const int tid = threadIdx.x, lane = tid & 63, w = tid >> 6;
    const int cl = lane & 15, rl = lane >> 4;

    const u16* Qb = QH + (size_t)bh * 131072;
    const u16* Kb = KH + (size_t)bh * 131072;
    const u16* Vb = VT + (size_t)bh * 131072;

    const int qrow0 = p * 128 + w * 32;

    s8v qf[2][2];
    #pragma unroll
    for (int mi = 0; mi < 2; ++mi)
        #pragma unroll
        for (int kf = 0; kf < 2; ++kf)
            qf[mi][kf] = *reinterpret_cast<const s8v*>(
                Qb + (size_t)(qrow0 + mi * 16 + cl) * 64 + kf * 32 + rl * 8);

    f4v o[2][4] = {};
    float mrun[8], lp[8];
    #pragma unroll
    for (int i = 0; i < 8; ++i) { mrun[i] = -1e30f; lp[i] = 0.f; }

    // swizzled LDS addressing (byte-based, keeps 16B alignment)
    auto kaddr = [&](int row, int colb) -> u16* {
        return (u16*)((char*)Kl + row * 128 + (colb ^ ((row & 7) << 4)));
    };
    auto vaddr = [&](int row, int colb) -> u16* {
        return (u16*)((char*)Vl + row * 256 + (colb ^ ((row & 15) << 4)));
    };

    auto loadT = [&](s8v* kst, s8v* vst, int kb0) {
        #pragma unroll
        for (int r = 0; r < 4; ++r) {
            const int f = r * 256 + tid;
            kst[r] = *reinterpret_cast<const s8v*>(Kb + (size_t)kb0 * 64 + f * 8);
            vst[r] = *reinterpret_cast<const s8v*>(
                Vb + (size_t)(f >> 4) * 2048 + kb0 + (f & 15) * 8);
        }
    };
    auto writeT = [&](const s8v* kst, const s8v* vst) {
        #pragma unroll
        for (int r = 0; r < 4; ++r) {
            const int f = r * 256 + tid;
            *reinterpret_cast<s8v*>(kaddr(f >> 3, (f & 7) * 16)) = kst[r];
            *reinterpret_cast<s8v*>(vaddr(f >> 4, (f & 15) * 16)) = vst[r];
        }
    };

    auto compute = [&]() {
        // S = Q K^T (operands from swizzled LDS)
        f4v sc[2][8] = {};
        #pragma unroll
        for (int ni = 0; ni < 8; ++ni)
            #pragma unroll
            for (int kf = 0; kf < 2; ++kf) {
                s8v kfr = *reinterpret_cast<const s8v*>(
                    kaddr(ni * 16 + cl, kf * 64 + rl * 16));
                sc[0][ni] = MFMA(qf[0][kf], kfr, sc[0][ni]);
                sc[1][ni] = MFMA(qf[1][kf], kfr, sc[1][ni]);
            }

        // online softmax (Q prescaled -> exp2 direct)
        float al[2][4];
        #pragma unroll
        for (int mi = 0; mi < 2; ++mi)
            #pragma unroll
            for (int r = 0; r < 4; ++r) {
                float rm = sc[mi][0][r];
                #pragma unroll
                for (int ni = 1; ni < 8; ++ni) rm = fmaxf(rm, sc[mi][ni][r]);
                rm = fmaxf(rm, __shfl_xor(rm, 1));
                rm = fmaxf(rm, __shfl_xor(rm, 2));
                rm = fmaxf(rm, __shfl_xor(rm, 4));
                rm = fmaxf(rm, __shfl_xor(rm, 8));
                const int idx = mi * 4 + r;
                const float mn = fmaxf(mrun[idx], rm);
                al[mi][r] = exp2f(mrun[idx] - mn);
                mrun[idx] = mn;
                float ps = 0.f;
                #pragma unroll
                for (int ni = 0; ni < 8; ++ni) {
                    sc[mi][ni][r] = exp2f(sc[mi][ni][r] - mn);
                    ps += sc[mi][ni][r];
                }
                lp[idx] = lp[idx] * al[mi][r] + ps;
            }
        #pragma unroll
        for (int mi = 0; mi < 2; ++mi)
            #pragma unroll
            for (int di = 0; di < 4; ++di)
                #pragma unroll
                for (int r = 0; r < 4; ++r) o[mi][di][r] *= al[mi][r];

        // PV in 32-key slices through per-wave LDS
        #pragma unroll
        for (int kfr = 0; kfr < 4; ++kfr) {
            #pragma unroll
            for (int mi = 0; mi < 2; ++mi)
                #pragma unroll
                for (int jj = 0; jj < 2; ++jj) {
                    const unsigned w0 = cvtpk(sc[mi][kfr * 2 + jj][0], sc[mi][kfr * 2 + jj][1]);
                    const unsigned w1 = cvtpk(sc[mi][kfr * 2 + jj][2], sc[mi][kfr * 2 + jj][3]);
                    const int col = jj * 16 + cl;
                    Pl[w][mi * 16 + rl * 4 + 0][col] = (u16)w0;
                    Pl[w][mi * 16 + rl * 4 + 1][col] = (u16)(w0 >> 16);
                    Pl[w][mi * 16 + rl * 4 + 2][col] = (u16)w1;
                    Pl[w][mi * 16 + rl * 4 + 3][col] = (u16)(w1 >> 16);
                }
            s8v pf0 = *reinterpret_cast<const s8v*>(&Pl[w][cl][rl * 8]);
            s8v pf1 = *reinterpret_cast<const s8v*>(&Pl[w][16 + cl][rl * 8]);
            #pragma unroll
            for (int di = 0; di < 4; ++di) {
                s8v vf = *reinterpret_cast<const s8v*>(
                    vaddr(di * 16 + cl, kfr * 64 + rl * 16));
                o[0][di] = MFMA(pf0, vf, o[0][di]);
                o[1][di] = MFMA(pf1, vf, o[1][di]);
            }
        }
    };

    // nt128 is even (2 or 4): stride-2 loop, two register staging sets.
    s8v kA[4], vA[4], kB[4], vB[4];
    loadT(kA, vA, kstart);
    for (int kt = 0; kt < nt128; kt += 2) {
        writeT(kA, vA);
        __syncthreads();
        loadT(kB, vB, kstart + (kt + 1) * 128);  // overlaps with compute below
        compute();
        __syncthreads();
        writeT(kB, vB);
        __syncthreads();
        if (kt + 2 < nt128) loadT(kA, vA, kstart + (kt + 2) * 128);
        compute();
        __syncthreads();
    }

    // write partial: Ohat = O/l (bf16), m & l (f32)
    const int slot = bh * 40 + POFF[p] + c;
    #pragma unroll
    for (int mi = 0; mi < 2; ++mi)
        #pragma unroll
        for (int r = 0; r < 4; ++r) {
            const int idx = mi * 4 + r;
            float ls = lp[idx];
            ls += __shfl_xor(ls, 1);
            ls += __shfl_xor(ls, 2);
            ls += __shfl_xor(ls, 4);
            ls += __shfl_xor(ls, 8);
            const float inv = 1.f / ls;
            const int rloc = w * 32 + mi * 16 + rl * 4 + r;
            if (cl == 0) {
                ML[(size_t)slot * 256 + rloc * 2 + 0] = mrun[idx];
                ML[(size_t)slot * 256 + rloc * 2 + 1] = ls;
            }
            #pragma unroll
            for (int di = 0; di < 4; ++di)
                Opart[(size_t)slot * 8192 + rloc * 64 + di * 16 + cl] =
                    f2bf(o[mi][di][r] * inv);
        }
}

// ---------------------------------------------------------------------------
// Kernel 2b: combine partials -> YH [b][t][c] bf16.
// ---------------------------------------------------------------------------
__global__ __launch_bounds__(256)
void attn_combine(const u16* __restrict__ Opart, const float* __restrict__ ML,
                  u16* __restrict__ YH)
{
    const int wg = blockIdx.x;
    const int bh = wg & 31;
    const int p  = wg >> 5;
    const int b = bh >> 3, h = bh & 7;
    const int nc = CPER[p >> 1];
    const int sb = bh * 40 + POFF[p];

    const int t = threadIdx.x;
    const int rloc = t >> 1;
    const int dh = (t & 1) * 32;

    float mc[4], lc[4];
    float M = -1e30f;
    for (int c = 0; c < nc; ++c) {
        mc[c] = ML[(size_t)(sb + c) * 256 + rloc * 2 + 0];
        lc[c] = ML[(size_t)(sb + c) * 256 + rloc * 2 + 1];
        M = fmaxf(M, mc[c]);
    }
    float L = 0.f, wgt[4];
    for (int c = 0; c < nc; ++c) {
        wgt[c] = lc[c] * exp2f(mc[c] - M);
        L += wgt[c];
    }
    const float invL = 1.f / L;
    for (int c = 0; c < nc; ++c) wgt[c] *= invL;

    f4v a[8] = {};
    for (int c = 0; c < nc; ++c) {
        const float wv = wgt[c];
        #pragma unroll
        for (int u = 0; u < 4; ++u) {
            s8v vv = *reinterpret_cast<const s8v*>(
                &Opart[(size_t)(sb + c) * 8192 + rloc * 64 + dh + u * 8]);
            #pragma unroll
            for (int e = 0; e < 4; ++e) a[u * 2][e]     += wv * bf2f((u16)vv[e]);
            #pragma unroll
            for (int e = 0; e < 4; ++e) a[u * 2 + 1][e] += wv * bf2f((u16)vv[e + 4]);
        }
    }

    const size_t ybase = ((size_t)b * 2048 + p * 128 + rloc) * 512 + h * 64 + dh;
    #pragma unroll
    for (int u = 0; u < 4; ++u) {
        s8v ov;
        #pragma unroll
        for (int e = 0; e < 4; ++e) ov[e]     = (short)f2bf(a[u * 2][e]);
        #pragma unroll
        for (int e = 0; e < 4; ++e) ov[e + 4] = (short)f2bf(a[u * 2 + 1][e]);
        *reinterpret_cast<s8v*>(YH + ybase + u * 8) = ov;
    }
}

// ---------------------------------------------------------------------------
// Kernel 3: output projection (transposed): C'[c][tok] = Wp^T . Y^T.
// ---------------------------------------------------------------------------
__global__ __launch_bounds__(256)
void out_proj(const u16* __restrict__ YH, const float* __restrict__ Wp,
              const float* __restrict__ bp, float* __restrict__ out)
{
    __shared__ u16 Al[128][40];
    __shared__ u16 Bl[128][40];

    const int bid = blockIdx.x;
    const int ct = bid >> 6;
    const int mt = bid & 63;
    const int c0 = ct << 7, m0 = mt << 7;

    const int tid = threadIdx.x, lane = tid & 63, w = tid >> 6;
    const int wr = (w >> 1) * 64, wc = (w & 1) * 64;
    const int cl = lane & 15, rl = lane >> 4;

    f4v acc[4][4] = {};

    const int lk = tid >> 3;
    const int lg = (tid & 7) * 16;
    const int br = tid >> 2;
    const int bq4 = (tid & 3) * 8;

    for (int k0 = 0; k0 < 512; k0 += 32) {
        {
            const float* g = Wp + (size_t)(k0 + lk) * 512 + c0 + lg;
            #pragma unroll
            for (int u = 0; u < 4; ++u) {
                f4v v = *reinterpret_cast<const f4v*>(g + u * 4);
                unsigned w0 = cvtpk(v[0], v[1]);
                unsigned w1 = cvtpk(v[2], v[3]);
                Al[lg + u * 4 + 0][lk] = (u16)w0;
                Al[lg + u * 4 + 1][lk] = (u16)(w0 >> 16);
                Al[lg + u * 4 + 2][lk] = (u16)w1;
                Al[lg + u * 4 + 3][lk] = (u16)(w1 >> 16);
            }
        }
        #pragma unroll
        for (int it = 0; it < 2; ++it) {
            const int row = br + it * 64;
            s8v v = *reinterpret_cast<const s8v*>(YH + (size_t)(m0 + row) * 512 + k0 + bq4);
            *reinterpret_cast<s8v*>(&Bl[row][bq4]) = v;
        }
        __syncthreads();
        s8v af[4], bfr[4];
        #pragma unroll
        for (int mi = 0; mi < 4; ++mi)
            af[mi] = *reinterpret_cast<const s8v*>(&Al[wr + mi * 16 + cl][rl * 8]);
        #pragma unroll
        for (int ni = 0; ni < 4; ++ni)
            bfr[ni] = *reinterpret_cast<const s8v*>(&Bl[wc + ni * 16 + cl][rl * 8]);
        #pragma unroll
        for (int mi = 0; mi < 4; ++mi)
            #pragma unroll
            for (int ni = 0; ni < 4; ++ni)
                acc[mi][ni] = MFMA(af[mi], bfr[ni], acc[mi][ni]);
        __syncthreads();
    }

    #pragma unroll
    for (int mi = 0; mi < 4; ++mi)
        #pragma unroll
        for (int r = 0; r < 4; ++r) {
            const int c = c0 + wr + mi * 16 + rl * 4 + r;   // D row = cout
            const float bv = bp[c];
            #pragma unroll
            for (int ni = 0; ni < 4; ++ni) {
                const int tok = m0 + wc + ni * 16 + cl;     // D col = token
                const int bb = tok >> 11, t = tok & 2047;
                const int vv = t >> 8, hw = t & 255;
                out[(size_t)(vv * 4 + bb) * 131072 + (size_t)c * 256 + hw] =
                    acc[mi][ni][r] + bv;
            }
        }
}

// ---------------------------------------------------------------------------
extern "C" void kernel_launch(void* const* d_in, const int* in_sizes, int n_in,
                              void* d_out, int out_size, void* d_ws, size_t ws_size,
                              hipStream_t stream)
{
    const float* q   = (const float*)d_in[0];
    const float* kv  = (const float*)d_in[1];
    const float* Wq  = (const float*)d_in[2];
    const float* bq  = (const float*)d_in[3];
    const float* Wkv = (const float*)d_in[4];
    const float* bkv = (const float*)d_in[5];
    const float* Wp  = (const float*)d_in[6];
    const float* bp  = (const float*)d_in[7];
    float* out = (float*)d_out;

    u16* ws = (u16*)d_ws;
    u16* QH = ws;                    // [4][8][2048][64] bf16, prescaled Q
    u16* KH = QH + 4194304;          // [4][8][2048][64]
    u16* VT = KH + 4194304;          // [4][8][64][2048]
    u16* YH = VT + 4194304;          // [4][2048][512]
    u16* Opart = YH + 4194304;       // [1280][128][64] bf16 = 20 MB
    float* ML  = (float*)(Opart + 10485760);  // [1280][128][2] f32 = 1.3 MB

    hipLaunchKernelGGL(qkv_proj, dim3(768), dim3(256), 0, stream,
                       q, kv, Wq, bq, Wkv, bkv, QH, KH, VT);
    hipLaunchKernelGGL(attn_part, dim3(1280), dim3(256), 0, stream,
                       QH, KH, VT, Opart, ML);
    hipLaunchKernelGGL(attn_combine, dim3(512), dim3(256), 0, stream,
                       Opart, ML, YH);
    hipLaunchKernelGGL(out_proj, dim3(256), dim3(256), 0, stream, YH, Wp, bp, out);
}

// Round 7
// 173.098 us; speedup vs baseline: 1.2637x; 1.2637x over previous
//
#include <hip/hip_runtime.h>
#include <hip/hip_bf16.h>
#include <cmath>

typedef unsigned short u16;
typedef __attribute__((ext_vector_type(8))) short s8v;    // 8 x bf16 bits
typedef __attribute__((ext_vector_type(4))) float f4v;
typedef __attribute__((ext_vector_type(4))) unsigned short u16x4;

#define MFMA(a,b,c) __builtin_amdgcn_mfma_f32_16x16x32_bf16((a),(b),(c),0,0,0)

__device__ __forceinline__ float bf2f(u16 u) {
    union { float f; unsigned i; } x; x.i = ((unsigned)u) << 16; return x.f;
}
__device__ __forceinline__ u16 f2bf(float f) {
    union { float f; unsigned i; } x; x.f = f;
    unsigned r = x.i + 0x7FFFu + ((x.i >> 16) & 1u);
    return (u16)(r >> 16);
}
__device__ __forceinline__ unsigned cvtpk(float lo, float hi) {
    unsigned r;
    asm("v_cvt_pk_bf16_f32 %0, %1, %2" : "=v"(r) : "v"(lo), "v"(hi));
    return r;
}
__device__ __forceinline__ void gload_lds16(const void* g, void* l) {
    __builtin_amdgcn_global_load_lds(
        (const __attribute__((address_space(1))) unsigned int*)g,
        (__attribute__((address_space(3))) unsigned int*)l, 16, 0, 0);
}

// chunks-per-qblock and per-p-tile prefix (512-key chunks, block-causal)
__constant__ int CPER[8]  = {1,1,2,2,3,3,4,4};
__constant__ int POFF[17] = {0,1,2,3,4,6,8,10,12,15,18,21,24,28,32,36,40};

// ---------------------------------------------------------------------------
// Kernel 1: fused QKV projection (f32 in -> bf16 MFMA -> bf16 out).
// Q output PRESCALED by 0.125*log2(e). Q,K: [b][h][T][d]; V: VT [b][h][d][T].
// ---------------------------------------------------------------------------
__global__ __launch_bounds__(256)
void qkv_proj(const float* __restrict__ q, const float* __restrict__ kv,
              const float* __restrict__ Wq, const float* __restrict__ bq,
              const float* __restrict__ Wkv, const float* __restrict__ bkv,
              u16* __restrict__ QH, u16* __restrict__ KH, u16* __restrict__ VT)
{
    __shared__ u16 Al[128][40];
    __shared__ u16 Bl[128][40];

    const int bid = blockIdx.x;
    const int mt = bid / 12, nt = bid - mt * 12;
    const int m0 = mt << 7, n0 = nt << 7;

    const int tid  = threadIdx.x;
    const int lane = tid & 63;
    const int w    = tid >> 6;
    const int wr = (w >> 1) * 64, wc = (w & 1) * 64;
    const int cl = lane & 15, rl = lane >> 4;

    const int bb  = m0 >> 11;
    const int t0  = m0 & 2047;
    const int vv  = t0 >> 8;
    const int hw0 = t0 & 255;

    const float* Abase = ((nt < 4) ? q : kv) + (size_t)(vv * 4 + bb) * 131072 + hw0;

    const float* W; const float* bias; int NW, wn0, dn0; u16* dst;
    if (nt < 4)      { W = Wq;  bias = bq;  NW = 512;  wn0 = n0;       dn0 = n0;        dst = QH; }
    else if (nt < 8) { W = Wkv; bias = bkv; NW = 1024; wn0 = n0 - 512; dn0 = n0 - 512;  dst = KH; }
    else             { W = Wkv; bias = bkv; NW = 1024; wn0 = n0 - 512; dn0 = n0 - 1024; dst = VT; }

    const float oscale = (nt < 4) ? 0.18033688011f : 1.0f;  // 0.125*log2(e)

    f4v acc[4][4] = {};

    const int lk = tid >> 3;
    const int lg = (tid & 7) * 16;

    for (int k0 = 0; k0 < 512; k0 += 32) {
        {
            const float* g = Abase + (size_t)(k0 + lk) * 256 + lg;
            #pragma unroll
            for (int u = 0; u < 4; ++u) {
                f4v v = *reinterpret_cast<const f4v*>(g + u * 4);
                unsigned w0 = cvtpk(v[0], v[1]);
                unsigned w1 = cvtpk(v[2], v[3]);
                Al[lg + u * 4 + 0][lk] = (u16)w0;
                Al[lg + u * 4 + 1][lk] = (u16)(w0 >> 16);
                Al[lg + u * 4 + 2][lk] = (u16)w1;
                Al[lg + u * 4 + 3][lk] = (u16)(w1 >> 16);
            }
        }
        {
            const float* g = W + (size_t)(k0 + lk) * NW + wn0 + lg;
            #pragma unroll
            for (int u = 0; u < 4; ++u) {
                f4v v = *reinterpret_cast<const f4v*>(g + u * 4);
                unsigned w0 = cvtpk(v[0], v[1]);
                unsigned w1 = cvtpk(v[2], v[3]);
                Bl[lg + u * 4 + 0][lk] = (u16)w0;
                Bl[lg + u * 4 + 1][lk] = (u16)(w0 >> 16);
                Bl[lg + u * 4 + 2][lk] = (u16)w1;
                Bl[lg + u * 4 + 3][lk] = (u16)(w1 >> 16);
            }
        }
        __syncthreads();
        s8v af[4], bf[4];
        #pragma unroll
        for (int mi = 0; mi < 4; ++mi)
            af[mi] = *reinterpret_cast<const s8v*>(&Al[wr + mi * 16 + cl][rl * 8]);
        #pragma unroll
        for (int ni = 0; ni < 4; ++ni)
            bf[ni] = *reinterpret_cast<const s8v*>(&Bl[wc + ni * 16 + cl][rl * 8]);
        #pragma unroll
        for (int mi = 0; mi < 4; ++mi)
            #pragma unroll
            for (int ni = 0; ni < 4; ++ni)
                acc[mi][ni] = MFMA(af[mi], bf[ni], acc[mi][ni]);
        __syncthreads();
    }

    if (nt < 8) {
        #pragma unroll
        for (int ni = 0; ni < 4; ++ni) {
            const int nl   = wc + ni * 16 + cl;
            const float bv = bias[wn0 + nl];
            const int cout = dn0 + nl;
            const int hh = cout >> 6, dd = cout & 63;
            const size_t obase = ((size_t)(bb * 8 + hh) * 2048) * 64 + dd;
            #pragma unroll
            for (int mi = 0; mi < 4; ++mi)
                #pragma unroll
                for (int r = 0; r < 4; ++r) {
                    const int m = m0 + wr + mi * 16 + rl * 4 + r;
                    const int t = m & 2047;
                    dst[obase + (size_t)t * 64] = f2bf((acc[mi][ni][r] + bv) * oscale);
                }
        }
    } else {
        #pragma unroll
        for (int ni = 0; ni < 4; ++ni) {
            const int nl   = wc + ni * 16 + cl;
            const float bv = bias[wn0 + nl];
            const int cout = dn0 + nl;
            const int hh = cout >> 6, dd = cout & 63;
            const size_t obase = ((size_t)(bb * 8 + hh) * 64 + dd) * 2048;
            #pragma unroll
            for (int mi = 0; mi < 4; ++mi) {
                const int m = m0 + wr + mi * 16 + rl * 4;
                const int t = m & 2047;
                u16x4 pk;
                #pragma unroll
                for (int r = 0; r < 4; ++r) pk[r] = f2bf(acc[mi][ni][r] + bv);
                *reinterpret_cast<u16x4*>(dst + obase + t) = pk;
            }
        }
    }
}

// ---------------------------------------------------------------------------
// Kernel 2a: attention partials. WG = (bh, 128-row q-tile p, 512-key chunk c).
// K/V staged via global_load_lds (16B, zero VGPRs) into double-buffered LDS.
// Source addresses pre-swizzled (rule #21): LDS linear dest + XOR-swizzled
// per-lane global source; reads apply the same XOR -> conflict-free b128.
// One barrier per tile; next tile's async loads issue before compute.
// ---------------------------------------------------------------------------
__global__ __launch_bounds__(256, 2)
void attn_part(const u16* __restrict__ QH, const u16* __restrict__ KH,
               const u16* __restrict__ VT,
               u16* __restrict__ Opart, float* __restrict__ ML)
{
    __shared__ __align__(16) u16 Kl[2][8192];  // [key][d], byte ^= (key&7)<<4
    __shared__ __align__(16) u16 Vl[2][8192];  // [d][key], byte ^= (d&15)<<4
    __shared__ u16 Pl[4][32][36];              // per-wave 32-key P slice

    const int wg = blockIdx.x;
    const int bh = wg & 31;      // XCD = wg&7 -> each XCD owns 4 bh (L2-resident)
    const int s  = wg >> 5;
    int p = 0;
    #pragma unroll
    for (int i = 0; i < 15; ++i) p += (s >= POFF[i + 1]) ? 1 : 0;
    const int c  = s - POFF[p];
    const int qb = p >> 1;
    const int kstart = c * 512;
    const int nk = min(512, (qb + 1) * 256 - kstart);
    const int nt128 = nk >> 7;

    const int tid = threadIdx.x, lane = tid & 63, w = tid >> 6;
    const int cl = lane & 15, rl = lane >> 4;

    const u16* Qb = QH + (size_t)bh * 131072;
    const u16* Kb = KH + (size_t)bh * 131072;
    const u16* Vb = VT + (size_t)bh * 131072;

    const int qrow0 = p * 128 + w * 32;

    s8v qf[2][2];
    #pragma unroll
    for (int mi = 0; mi < 2; ++mi)
        #pragma unroll
        for (int kf = 0; kf < 2; ++kf)
            qf[mi][kf] = *reinterpret_cast<const s8v*>(
                Qb + (size_t)(qrow0 + mi * 16 + cl) * 64 + kf * 32 + rl * 8);

    // per-thread pre-swizzled source offsets (call i covers LDS slot f*16)
    unsigned kofs[4], vofs[4];
    #pragma unroll
    for (int i = 0; i < 4; ++i) {
        const int f = w * 256 + i * 64 + lane;
        const int krow = f >> 3;
        kofs[i] = krow * 128 + (((f & 7) * 16) ^ ((krow & 7) << 4));
        const int vrow = f >> 4;
        vofs[i] = vrow * 4096 + (((f & 15) * 16) ^ ((vrow & 15) << 4));
    }

#define ISSUE(bufi, kb0_) do {                                               \
        const char* kG = (const char*)Kb + (size_t)(kb0_) * 128;             \
        const char* vG = (const char*)Vb + (size_t)(kb0_) * 2;               \
        char* kL = (char*)&Kl[bufi][0] + w * 4096;                           \
        char* vL = (char*)&Vl[bufi][0] + w * 4096;                           \
        _Pragma("unroll")                                                    \
        for (int i_ = 0; i_ < 4; ++i_) {                                     \
            gload_lds16(kG + kofs[i_], kL + i_ * 1024);                      \
            gload_lds16(vG + vofs[i_], vL + i_ * 1024);                      \
        }                                                                    \
    } while (0)

    f4v o[2][4] = {};
    float mrun[8], lp[8];
    #pragma unroll
    for (int i = 0; i < 8; ++i) { mrun[i] = -1e30f; lp[i] = 0.f; }

    ISSUE(0, kstart);

    for (int kt = 0; kt < nt128; ++kt) {
        asm volatile("s_waitcnt vmcnt(0)" ::: "memory");
        __builtin_amdgcn_sched_barrier(0);
        __syncthreads();
        if (kt + 1 < nt128) ISSUE((kt + 1) & 1, kstart + (kt + 1) * 128);

        const char* Kbase = (const char*)&Kl[kt & 1][0];
        const char* Vbase = (const char*)&Vl[kt & 1][0];

        // S = Q K^T (swizzled LDS reads)
        f4v sc[2][8] = {};
        #pragma unroll
        for (int ni = 0; ni < 8; ++ni)
            #pragma unroll
            for (int kf = 0; kf < 2; ++kf) {
                const int row = ni * 16 + cl;
                s8v kfr = *reinterpret_cast<const s8v*>(
                    Kbase + row * 128 + ((kf * 64 + rl * 16) ^ ((row & 7) << 4)));
                sc[0][ni] = MFMA(qf[0][kf], kfr, sc[0][ni]);
                sc[1][ni] = MFMA(qf[1][kf], kfr, sc[1][ni]);
            }

        // online softmax (Q prescaled -> exp2 direct)
        float al[2][4];
        #pragma unroll
        for (int mi = 0; mi < 2; ++mi)
            #pragma unroll
            for (int r = 0; r < 4; ++r) {
                float rm = sc[mi][0][r];
                #pragma unroll
                for (int ni = 1; ni < 8; ++ni) rm = fmaxf(rm, sc[mi][ni][r]);
                rm = fmaxf(rm, __shfl_xor(rm, 1));
                rm = fmaxf(rm, __shfl_xor(rm, 2));
                rm = fmaxf(rm, __shfl_xor(rm, 4));
                rm = fmaxf(rm, __shfl_xor(rm, 8));
                const int idx = mi * 4 + r;
                const float mn = fmaxf(mrun[idx], rm);
                al[mi][r] = exp2f(mrun[idx] - mn);
                mrun[idx] = mn;
                float ps = 0.f;
                #pragma unroll
                for (int ni = 0; ni < 8; ++ni) {
                    sc[mi][ni][r] = exp2f(sc[mi][ni][r] - mn);
                    ps += sc[mi][ni][r];
                }
                lp[idx] = lp[idx] * al[mi][r] + ps;
            }
        #pragma unroll
        for (int mi = 0; mi < 2; ++mi)
            #pragma unroll
            for (int di = 0; di < 4; ++di)
                #pragma unroll
                for (int r = 0; r < 4; ++r) o[mi][di][r] *= al[mi][r];

        // PV in 32-key slices through per-wave LDS
        #pragma unroll
        for (int kfr = 0; kfr < 4; ++kfr) {
            #pragma unroll
            for (int mi = 0; mi < 2; ++mi)
                #pragma unroll
                for (int jj = 0; jj < 2; ++jj) {
                    const unsigned w0 = cvtpk(sc[mi][kfr * 2 + jj][0], sc[mi][kfr * 2 + jj][1]);
                    const unsigned w1 = cvtpk(sc[mi][kfr * 2 + jj][2], sc[mi][kfr * 2 + jj][3]);
                    const int col = jj * 16 + cl;
                    Pl[w][mi * 16 + rl * 4 + 0][col] = (u16)w0;
                    Pl[w][mi * 16 + rl * 4 + 1][col] = (u16)(w0 >> 16);
                    Pl[w][mi * 16 + rl * 4 + 2][col] = (u16)w1;
                    Pl[w][mi * 16 + rl * 4 + 3][col] = (u16)(w1 >> 16);
                }
            s8v pf0 = *reinterpret_cast<const s8v*>(&Pl[w][cl][rl * 8]);
            s8v pf1 = *reinterpret_cast<const s8v*>(&Pl[w][16 + cl][rl * 8]);
            #pragma unroll
            for (int di = 0; di < 4; ++di) {
                const int row = di * 16 + cl;
                s8v vf = *reinterpret_cast<const s8v*>(
                    Vbase + row * 256 + ((kfr * 64 + rl * 16) ^ ((row & 15) << 4)));
                o[0][di] = MFMA(pf0, vf, o[0][di]);
                o[1][di] = MFMA(pf1, vf, o[1][di]);
            }
        }
    }
#undef ISSUE

    // write partial: Ohat = O/l (bf16), m & l (f32)
    const int slot = bh * 40 + POFF[p] + c;
    #pragma unroll
    for (int mi = 0; mi < 2; ++mi)
        #pragma unroll
        for (int r = 0; r < 4; ++r) {
            const int idx = mi * 4 + r;
            float ls = lp[idx];
            ls += __shfl_xor(ls, 1);
            ls += __shfl_xor(ls, 2);
            ls += __shfl_xor(ls, 4);
            ls += __shfl_xor(ls, 8);
            const float inv = 1.f / ls;
            const int rloc = w * 32 + mi * 16 + rl * 4 + r;
            if (cl == 0) {
                ML[(size_t)slot * 256 + rloc * 2 + 0] = mrun[idx];
                ML[(size_t)slot * 256 + rloc * 2 + 1] = ls;
            }
            #pragma unroll
            for (int di = 0; di < 4; ++di)
                Opart[(size_t)slot * 8192 + rloc * 64 + di * 16 + cl] =
                    f2bf(o[mi][di][r] * inv);
        }
}

// ---------------------------------------------------------------------------
// Kernel 2b: combine partials -> YH [b][t][c] bf16.
// ---------------------------------------------------------------------------
__global__ __launch_bounds__(256)
void attn_combine(const u16* __restrict__ Opart, const float* __restrict__ ML,
                  u16* __restrict__ YH)
{
    const int wg = blockIdx.x;
    const int bh = wg & 31;
    const int p  = wg >> 5;
    const int b = bh >> 3, h = bh & 7;
    const int nc = CPER[p >> 1];
    const int sb = bh * 40 + POFF[p];

    const int t = threadIdx.x;
    const int rloc = t >> 1;
    const int dh = (t & 1) * 32;

    float mc[4], lc[4];
    float M = -1e30f;
    for (int c = 0; c < nc; ++c) {
        mc[c] = ML[(size_t)(sb + c) * 256 + rloc * 2 + 0];
        lc[c] = ML[(size_t)(sb + c) * 256 + rloc * 2 + 1];
        M = fmaxf(M, mc[c]);
    }
    float L = 0.f, wgt[4];
    for (int c = 0; c < nc; ++c) {
        wgt[c] = lc[c] * exp2f(mc[c] - M);
        L += wgt[c];
    }
    const float invL = 1.f / L;
    for (int c = 0; c < nc; ++c) wgt[c] *= invL;

    f4v a[8] = {};
    for (int c = 0; c < nc; ++c) {
        const float wv = wgt[c];
        #pragma unroll
        for (int u = 0; u < 4; ++u) {
            s8v vv = *reinterpret_cast<const s8v*>(
                &Opart[(size_t)(sb + c) * 8192 + rloc * 64 + dh + u * 8]);
            #pragma unroll
            for (int e = 0; e < 4; ++e) a[u * 2][e]     += wv * bf2f((u16)vv[e]);
            #pragma unroll
            for (int e = 0; e < 4; ++e) a[u * 2 + 1][e] += wv * bf2f((u16)vv[e + 4]);
        }
    }

    const size_t ybase = ((size_t)b * 2048 + p * 128 + rloc) * 512 + h * 64 + dh;
    #pragma unroll
    for (int u = 0; u < 4; ++u) {
        s8v ov;
        #pragma unroll
        for (int e = 0; e < 4; ++e) ov[e]     = (short)f2bf(a[u * 2][e]);
        #pragma unroll
        for (int e = 0; e < 4; ++e) ov[e + 4] = (short)f2bf(a[u * 2 + 1][e]);
        *reinterpret_cast<s8v*>(YH + ybase + u * 8) = ov;
    }
}

// ---------------------------------------------------------------------------
// Kernel 3: output projection (transposed): C'[c][tok] = Wp^T . Y^T.
// ---------------------------------------------------------------------------
__global__ __launch_bounds__(256)
void out_proj(const u16* __restrict__ YH, const float* __restrict__ Wp,
              const float* __restrict__ bp, float* __restrict__ out)
{
    __shared__ u16 Al[128][40];
    __shared__ u16 Bl[128][40];

    const int bid = blockIdx.x;
    const int ct = bid >> 6;
    const int mt = bid & 63;
    const int c0 = ct << 7, m0 = mt << 7;

    const int tid = threadIdx.x, lane = tid & 63, w = tid >> 6;
    const int wr = (w >> 1) * 64, wc = (w & 1) * 64;
    const int cl = lane & 15, rl = lane >> 4;

    f4v acc[4][4] = {};

    const int lk = tid >> 3;
    const int lg = (tid & 7) * 16;
    const int br = tid >> 2;
    const int bq4 = (tid & 3) * 8;

    for (int k0 = 0; k0 < 512; k0 += 32) {
        {
            const float* g = Wp + (size_t)(k0 + lk) * 512 + c0 + lg;
            #pragma unroll
            for (int u = 0; u < 4; ++u) {
                f4v v = *reinterpret_cast<const f4v*>(g + u * 4);
                unsigned w0 = cvtpk(v[0], v[1]);
                unsigned w1 = cvtpk(v[2], v[3]);
                Al[lg + u * 4 + 0][lk] = (u16)w0;
                Al[lg + u * 4 + 1][lk] = (u16)(w0 >> 16);
                Al[lg + u * 4 + 2][lk] = (u16)w1;
                Al[lg + u * 4 + 3][lk] = (u16)(w1 >> 16);
            }
        }
        #pragma unroll
        for (int it = 0; it < 2; ++it) {
            const int row = br + it * 64;
            s8v v = *reinterpret_cast<const s8v*>(YH + (size_t)(m0 + row) * 512 + k0 + bq4);
            *reinterpret_cast<s8v*>(&Bl[row][bq4]) = v;
        }
        __syncthreads();
        s8v af[4], bfr[4];
        #pragma unroll
        for (int mi = 0; mi < 4; ++mi)
            af[mi] = *reinterpret_cast<const s8v*>(&Al[wr + mi * 16 + cl][rl * 8]);
        #pragma unroll
        for (int ni = 0; ni < 4; ++ni)
            bfr[ni] = *reinterpret_cast<const s8v*>(&Bl[wc + ni * 16 + cl][rl * 8]);
        #pragma unroll
        for (int mi = 0; mi < 4; ++mi)
            #pragma unroll
            for (int ni = 0; ni < 4; ++ni)
                acc[mi][ni] = MFMA(af[mi], bfr[ni], acc[mi][ni]);
        __syncthreads();
    }

    #pragma unroll
    for (int mi = 0; mi < 4; ++mi)
        #pragma unroll
        for (int r = 0; r < 4; ++r) {
            const int c = c0 + wr + mi * 16 + rl * 4 + r;   // D row = cout
            const float bv = bp[c];
            #pragma unroll
            for (int ni = 0; ni < 4; ++ni) {
                const int tok = m0 + wc + ni * 16 + cl;     // D col = token
                const int bb = tok >> 11, t = tok & 2047;
                const int vv = t >> 8, hw = t & 255;
                out[(size_t)(vv * 4 + bb) * 131072 + (size_t)c * 256 + hw] =
                    acc[mi][ni][r] + bv;
            }
        }
}

// ---------------------------------------------------------------------------
extern "C" void kernel_launch(void* const* d_in, const int* in_sizes, int n_in,
                              void* d_out, int out_size, void* d_ws, size_t ws_size,
                              hipStream_t stream)
{
    const float* q   = (const float*)d_in[0];
    const float* kv  = (const float*)d_in[1];
    const float* Wq  = (const float*)d_in[2];
    const float* bq  = (const float*)d_in[3];
    const float* Wkv = (const float*)d_in[4];
    const float* bkv = (const float*)d_in[5];
    const float* Wp  = (const float*)d_in[6];
    const float* bp  = (const float*)d_in[7];
    float* out = (float*)d_out;

    u16* ws = (u16*)d_ws;
    u16* QH = ws;                    // [4][8][2048][64] bf16, prescaled Q
    u16* KH = QH + 4194304;          // [4][8][2048][64]
    u16* VT = KH + 4194304;          // [4][8][64][2048]
    u16* YH = VT + 4194304;          // [4][2048][512]
    u16* Opart = YH + 4194304;       // [1280][128][64] bf16 = 20 MB
    float* ML  = (float*)(Opart + 10485760);  // [1280][128][2] f32 = 1.3 MB

    hipLaunchKernelGGL(qkv_proj, dim3(768), dim3(256), 0, stream,
                       q, kv, Wq, bq, Wkv, bkv, QH, KH, VT);
    hipLaunchKernelGGL(attn_part, dim3(1280), dim3(256), 0, stream,
                       QH, KH, VT, Opart, ML);
    hipLaunchKernelGGL(attn_combine, dim3(512), dim3(256), 0, stream,
                       Opart, ML, YH);
    hipLaunchKernelGGL(out_proj, dim3(256), dim3(256), 0, stream, YH, Wp, bp, out);
}

// Round 8
// 144.291 us; speedup vs baseline: 1.5160x; 1.1996x over previous
//
#include <hip/hip_runtime.h>
#include <hip/hip_bf16.h>
#include <cmath>

typedef unsigned short u16;
typedef __attribute__((ext_vector_type(8))) short s8v;    // 8 x bf16 bits
typedef __attribute__((ext_vector_type(4))) float f4v;
typedef __attribute__((ext_vector_type(4))) unsigned short u16x4;

#define MFMA(a,b,c) __builtin_amdgcn_mfma_f32_16x16x32_bf16((a),(b),(c),0,0,0)

__device__ __forceinline__ float bf2f(u16 u) {
    union { float f; unsigned i; } x; x.i = ((unsigned)u) << 16; return x.f;
}
__device__ __forceinline__ u16 f2bf(float f) {
    union { float f; unsigned i; } x; x.f = f;
    unsigned r = x.i + 0x7FFFu + ((x.i >> 16) & 1u);
    return (u16)(r >> 16);
}
__device__ __forceinline__ unsigned cvtpk(float lo, float hi) {
    unsigned r;
    asm("v_cvt_pk_bf16_f32 %0, %1, %2" : "=v"(r) : "v"(lo), "v"(hi));
    return r;
}
__device__ __forceinline__ void gload_lds16(const void* g, void* l) {
    __builtin_amdgcn_global_load_lds(
        (const __attribute__((address_space(1))) unsigned int*)g,
        (__attribute__((address_space(3))) unsigned int*)l, 16, 0, 0);
}
// swizzled byte offset into a [128 rows][128 B] LDS tile; bijective per row,
// write side (rows 16 apart) and read side (rows consecutive) both conflict-free
__device__ __forceinline__ int swb(int row, int colb) {
    return row * 128 + (colb ^ ((((row >> 4) ^ row) & 7) << 4));
}

// chunks-per-qblock and per-p-tile prefix (512-key chunks, block-causal)
__constant__ int CPER[8]  = {1,1,2,2,3,3,4,4};
__constant__ int POFF[17] = {0,1,2,3,4,6,8,10,12,15,18,21,24,28,32,36,40};

// ---------------------------------------------------------------------------
// Kernel 1: fused QKV projection (f32 in -> bf16 MFMA -> bf16 out).
// Q output PRESCALED by 0.125*log2(e). Q,K: [b][h][T][d]; V: VT [b][h][d][T].
// XCD-chunked block map: all 12 n-tiles of an m-panel run on one XCD.
// LDS tiles XOR-swizzled [128][64] u16 -> conflict-free staging + reads.
// ---------------------------------------------------------------------------
__global__ __launch_bounds__(256)
void qkv_proj(const float* __restrict__ q, const float* __restrict__ kv,
              const float* __restrict__ Wq, const float* __restrict__ bq,
              const float* __restrict__ Wkv, const float* __restrict__ bkv,
              u16* __restrict__ QH, u16* __restrict__ KH, u16* __restrict__ VT)
{
    __shared__ __align__(16) u16 Al[128 * 64];
    __shared__ __align__(16) u16 Bl[128 * 64];

    const int bid = blockIdx.x;
    const int x = bid & 7, i = bid >> 3;     // XCD-chunked: same-mt consecutive
    const int mt = x + 8 * (i / 12);
    const int nt = i % 12;
    const int m0 = mt << 7, n0 = nt << 7;

    const int tid  = threadIdx.x;
    const int lane = tid & 63;
    const int w    = tid >> 6;
    const int wr = (w >> 1) * 64, wc = (w & 1) * 64;
    const int cl = lane & 15, rl = lane >> 4;

    const int bb  = m0 >> 11;
    const int t0  = m0 & 2047;
    const int vv  = t0 >> 8;
    const int hw0 = t0 & 255;

    const float* Abase = ((nt < 4) ? q : kv) + (size_t)(vv * 4 + bb) * 131072 + hw0;

    const float* W; const float* bias; int NW, wn0, dn0; u16* dst;
    if (nt < 4)      { W = Wq;  bias = bq;  NW = 512;  wn0 = n0;       dn0 = n0;        dst = QH; }
    else if (nt < 8) { W = Wkv; bias = bkv; NW = 1024; wn0 = n0 - 512; dn0 = n0 - 512;  dst = KH; }
    else             { W = Wkv; bias = bkv; NW = 1024; wn0 = n0 - 512; dn0 = n0 - 1024; dst = VT; }

    const float oscale = (nt < 4) ? 0.18033688011f : 1.0f;  // 0.125*log2(e)

    f4v acc[4][4] = {};

    const int lk = tid >> 3;          // k within tile: 0..31
    const int lg = (tid & 7) * 16;    // m/n group base

    for (int k0 = 0; k0 < 512; k0 += 32) {
        {
            const float* g = Abase + (size_t)(k0 + lk) * 256 + lg;
            #pragma unroll
            for (int u = 0; u < 4; ++u) {
                f4v v = *reinterpret_cast<const f4v*>(g + u * 4);
                unsigned w0 = cvtpk(v[0], v[1]);
                unsigned w1 = cvtpk(v[2], v[3]);
                *(u16*)((char*)Al + swb(lg + u * 4 + 0, lk * 2)) = (u16)w0;
                *(u16*)((char*)Al + swb(lg + u * 4 + 1, lk * 2)) = (u16)(w0 >> 16);
                *(u16*)((char*)Al + swb(lg + u * 4 + 2, lk * 2)) = (u16)w1;
                *(u16*)((char*)Al + swb(lg + u * 4 + 3, lk * 2)) = (u16)(w1 >> 16);
            }
        }
        {
            const float* g = W + (size_t)(k0 + lk) * NW + wn0 + lg;
            #pragma unroll
            for (int u = 0; u < 4; ++u) {
                f4v v = *reinterpret_cast<const f4v*>(g + u * 4);
                unsigned w0 = cvtpk(v[0], v[1]);
                unsigned w1 = cvtpk(v[2], v[3]);
                *(u16*)((char*)Bl + swb(lg + u * 4 + 0, lk * 2)) = (u16)w0;
                *(u16*)((char*)Bl + swb(lg + u * 4 + 1, lk * 2)) = (u16)(w0 >> 16);
                *(u16*)((char*)Bl + swb(lg + u * 4 + 2, lk * 2)) = (u16)w1;
                *(u16*)((char*)Bl + swb(lg + u * 4 + 3, lk * 2)) = (u16)(w1 >> 16);
            }
        }
        __syncthreads();
        s8v af[4], bf[4];
        #pragma unroll
        for (int mi = 0; mi < 4; ++mi)
            af[mi] = *(const s8v*)((const char*)Al + swb(wr + mi * 16 + cl, rl * 16));
        #pragma unroll
        for (int ni = 0; ni < 4; ++ni)
            bf[ni] = *(const s8v*)((const char*)Bl + swb(wc + ni * 16 + cl, rl * 16));
        #pragma unroll
        for (int mi = 0; mi < 4; ++mi)
            #pragma unroll
            for (int ni = 0; ni < 4; ++ni)
                acc[mi][ni] = MFMA(af[mi], bf[ni], acc[mi][ni]);
        __syncthreads();
    }

    if (nt < 8) {
        #pragma unroll
        for (int ni = 0; ni < 4; ++ni) {
            const int nl   = wc + ni * 16 + cl;
            const float bv = bias[wn0 + nl];
            const int cout = dn0 + nl;
            const int hh = cout >> 6, dd = cout & 63;
            const size_t obase = ((size_t)(bb * 8 + hh) * 2048) * 64 + dd;
            #pragma unroll
            for (int mi = 0; mi < 4; ++mi)
                #pragma unroll
                for (int r = 0; r < 4; ++r) {
                    const int m = m0 + wr + mi * 16 + rl * 4 + r;
                    const int t = m & 2047;
                    dst[obase + (size_t)t * 64] = f2bf((acc[mi][ni][r] + bv) * oscale);
                }
        }
    } else {
        #pragma unroll
        for (int ni = 0; ni < 4; ++ni) {
            const int nl   = wc + ni * 16 + cl;
            const float bv = bias[wn0 + nl];
            const int cout = dn0 + nl;
            const int hh = cout >> 6, dd = cout & 63;
            const size_t obase = ((size_t)(bb * 8 + hh) * 64 + dd) * 2048;
            #pragma unroll
            for (int mi = 0; mi < 4; ++mi) {
                const int m = m0 + wr + mi * 16 + rl * 4;
                const int t = m & 2047;
                u16x4 pk;
                #pragma unroll
                for (int r = 0; r < 4; ++r) pk[r] = f2bf(acc[mi][ni][r] + bv);
                *reinterpret_cast<u16x4*>(dst + obase + t) = pk;
            }
        }
    }
}

// ---------------------------------------------------------------------------
// Kernel 2a: attention partials. WG = (bh, 128-row q-tile p, 512-key chunk c).
// K/V staged via global_load_lds (16B) into double-buffered swizzled LDS.
// ---------------------------------------------------------------------------
__global__ __launch_bounds__(256, 2)
void attn_part(const u16* __restrict__ QH, const u16* __restrict__ KH,
               const u16* __restrict__ VT,
               u16* __restrict__ Opart, float* __restrict__ ML)
{
    __shared__ __align__(16) u16 Kl[2][8192];  // [key][d], byte ^= (key&7)<<4
    __shared__ __align__(16) u16 Vl[2][8192];  // [d][key], byte ^= (d&15)<<4
    __shared__ u16 Pl[4][32][36];              // per-wave 32-key P slice

    const int wg = blockIdx.x;
    const int bh = wg & 31;
    const int s  = wg >> 5;
    int p = 0;
    #pragma unroll
    for (int i = 0; i < 15; ++i) p += (s >= POFF[i + 1]) ? 1 : 0;
    const int c  = s - POFF[p];
    const int qb = p >> 1;
    const int kstart = c * 512;
    const int nk = min(512, (qb + 1) * 256 - kstart);
    const int nt128 = nk >> 7;

    const int tid = threadIdx.x, lane = tid & 63, w = tid >> 6;
    const int cl = lane & 15, rl = lane >> 4;

    const u16* Qb = QH + (size_t)bh * 131072;
    const u16* Kb = KH + (size_t)bh * 131072;
    const u16* Vb = VT + (size_t)bh * 131072;

    const int qrow0 = p * 128 + w * 32;

    s8v qf[2][2];
    #pragma unroll
    for (int mi = 0; mi < 2; ++mi)
        #pragma unroll
        for (int kf = 0; kf < 2; ++kf)
            qf[mi][kf] = *reinterpret_cast<const s8v*>(
                Qb + (size_t)(qrow0 + mi * 16 + cl) * 64 + kf * 32 + rl * 8);

    // per-thread pre-swizzled source offsets (call i covers LDS slot f*16)
    unsigned kofs[4], vofs[4];
    #pragma unroll
    for (int i = 0; i < 4; ++i) {
        const int f = w * 256 + i * 64 + lane;
        const int krow = f >> 3;
        kofs[i] = krow * 128 + (((f & 7) * 16) ^ ((krow & 7) << 4));
        const int vrow = f >> 4;
        vofs[i] = vrow * 4096 + (((f & 15) * 16) ^ ((vrow & 15) << 4));
    }

#define ISSUE(bufi, kb0_) do {                                               \
        const char* kG = (const char*)Kb + (size_t)(kb0_) * 128;             \
        const char* vG = (const char*)Vb + (size_t)(kb0_) * 2;               \
        char* kL = (char*)&Kl[bufi][0] + w * 4096;                           \
        char* vL = (char*)&Vl[bufi][0] + w * 4096;                           \
        _Pragma("unroll")                                                    \
        for (int i_ = 0; i_ < 4; ++i_) {                                     \
            gload_lds16(kG + kofs[i_], kL + i_ * 1024);                      \
            gload_lds16(vG + vofs[i_], vL + i_ * 1024);                      \
        }                                                                    \
    } while (0)

    f4v o[2][4] = {};
    float mrun[8], lp[8];
    #pragma unroll
    for (int i = 0; i < 8; ++i) { mrun[i] = -1e30f; lp[i] = 0.f; }

    ISSUE(0, kstart);

    for (int kt = 0; kt < nt128; ++kt) {
        asm volatile("s_waitcnt vmcnt(0)" ::: "memory");
        __builtin_amdgcn_sched_barrier(0);
        __syncthreads();
        if (kt + 1 < nt128) ISSUE((kt + 1) & 1, kstart + (kt + 1) * 128);

        const char* Kbase = (const char*)&Kl[kt & 1][0];
        const char* Vbase = (const char*)&Vl[kt & 1][0];

        // S = Q K^T (swizzled LDS reads)
        f4v sc[2][8] = {};
        #pragma unroll
        for (int ni = 0; ni < 8; ++ni)
            #pragma unroll
            for (int kf = 0; kf < 2; ++kf) {
                const int row = ni * 16 + cl;
                s8v kfr = *reinterpret_cast<const s8v*>(
                    Kbase + row * 128 + ((kf * 64 + rl * 16) ^ ((row & 7) << 4)));
                sc[0][ni] = MFMA(qf[0][kf], kfr, sc[0][ni]);
                sc[1][ni] = MFMA(qf[1][kf], kfr, sc[1][ni]);
            }

        // online softmax (Q prescaled -> exp2 direct)
        float al[2][4];
        #pragma unroll
        for (int mi = 0; mi < 2; ++mi)
            #pragma unroll
            for (int r = 0; r < 4; ++r) {
                float rm = sc[mi][0][r];
                #pragma unroll
                for (int ni = 1; ni < 8; ++ni) rm = fmaxf(rm, sc[mi][ni][r]);
                rm = fmaxf(rm, __shfl_xor(rm, 1));
                rm = fmaxf(rm, __shfl_xor(rm, 2));
                rm = fmaxf(rm, __shfl_xor(rm, 4));
                rm = fmaxf(rm, __shfl_xor(rm, 8));
                const int idx = mi * 4 + r;
                const float mn = fmaxf(mrun[idx], rm);
                al[mi][r] = exp2f(mrun[idx] - mn);
                mrun[idx] = mn;
                float ps = 0.f;
                #pragma unroll
                for (int ni = 0; ni < 8; ++ni) {
                    sc[mi][ni][r] = exp2f(sc[mi][ni][r] - mn);
                    ps += sc[mi][ni][r];
                }
                lp[idx] = lp[idx] * al[mi][r] + ps;
            }
        #pragma unroll
        for (int mi = 0; mi < 2; ++mi)
            #pragma unroll
            for (int di = 0; di < 4; ++di)
                #pragma unroll
                for (int r = 0; r < 4; ++r) o[mi][di][r] *= al[mi][r];

        // PV in 32-key slices through per-wave LDS
        #pragma unroll
        for (int kfr = 0; kfr < 4; ++kfr) {
            #pragma unroll
            for (int mi = 0; mi < 2; ++mi)
                #pragma unroll
                for (int jj = 0; jj < 2; ++jj) {
                    const unsigned w0 = cvtpk(sc[mi][kfr * 2 + jj][0], sc[mi][kfr * 2 + jj][1]);
                    const unsigned w1 = cvtpk(sc[mi][kfr * 2 + jj][2], sc[mi][kfr * 2 + jj][3]);
                    const int col = jj * 16 + cl;
                    Pl[w][mi * 16 + rl * 4 + 0][col] = (u16)w0;
                    Pl[w][mi * 16 + rl * 4 + 1][col] = (u16)(w0 >> 16);
                    Pl[w][mi * 16 + rl * 4 + 2][col] = (u16)w1;
                    Pl[w][mi * 16 + rl * 4 + 3][col] = (u16)(w1 >> 16);
                }
            s8v pf0 = *reinterpret_cast<const s8v*>(&Pl[w][cl][rl * 8]);
            s8v pf1 = *reinterpret_cast<const s8v*>(&Pl[w][16 + cl][rl * 8]);
            #pragma unroll
            for (int di = 0; di < 4; ++di) {
                const int row = di * 16 + cl;
                s8v vf = *reinterpret_cast<const s8v*>(
                    Vbase + row * 256 + ((kfr * 64 + rl * 16) ^ ((row & 15) << 4)));
                o[0][di] = MFMA(pf0, vf, o[0][di]);
                o[1][di] = MFMA(pf1, vf, o[1][di]);
            }
        }
    }
#undef ISSUE

    // write partial: Ohat = O/l (bf16), m & l (f32)
    const int slot = bh * 40 + POFF[p] + c;
    #pragma unroll
    for (int mi = 0; mi < 2; ++mi)
        #pragma unroll
        for (int r = 0; r < 4; ++r) {
            const int idx = mi * 4 + r;
            float ls = lp[idx];
            ls += __shfl_xor(ls, 1);
            ls += __shfl_xor(ls, 2);
            ls += __shfl_xor(ls, 4);
            ls += __shfl_xor(ls, 8);
            const float inv = 1.f / ls;
            const int rloc = w * 32 + mi * 16 + rl * 4 + r;
            if (cl == 0) {
                ML[(size_t)slot * 256 + rloc * 2 + 0] = mrun[idx];
                ML[(size_t)slot * 256 + rloc * 2 + 1] = ls;
            }
            #pragma unroll
            for (int di = 0; di < 4; ++di)
                Opart[(size_t)slot * 8192 + rloc * 64 + di * 16 + cl] =
                    f2bf(o[mi][di][r] * inv);
        }
}

// ---------------------------------------------------------------------------
// Kernel 2b: combine partials -> YH [b][t][c] bf16.
// ---------------------------------------------------------------------------
__global__ __launch_bounds__(256)
void attn_combine(const u16* __restrict__ Opart, const float* __restrict__ ML,
                  u16* __restrict__ YH)
{
    const int wg = blockIdx.x;
    const int bh = wg & 31;
    const int p  = wg >> 5;
    const int b = bh >> 3, h = bh & 7;
    const int nc = CPER[p >> 1];
    const int sb = bh * 40 + POFF[p];

    const int t = threadIdx.x;
    const int rloc = t >> 1;
    const int dh = (t & 1) * 32;

    float mc[4], lc[4];
    float M = -1e30f;
    for (int c = 0; c < nc; ++c) {
        mc[c] = ML[(size_t)(sb + c) * 256 + rloc * 2 + 0];
        lc[c] = ML[(size_t)(sb + c) * 256 + rloc * 2 + 1];
        M = fmaxf(M, mc[c]);
    }
    float L = 0.f, wgt[4];
    for (int c = 0; c < nc; ++c) {
        wgt[c] = lc[c] * exp2f(mc[c] - M);
        L += wgt[c];
    }
    const float invL = 1.f / L;
    for (int c = 0; c < nc; ++c) wgt[c] *= invL;

    f4v a[8] = {};
    for (int c = 0; c < nc; ++c) {
        const float wv = wgt[c];
        #pragma unroll
        for (int u = 0; u < 4; ++u) {
            s8v vv = *reinterpret_cast<const s8v*>(
                &Opart[(size_t)(sb + c) * 8192 + rloc * 64 + dh + u * 8]);
            #pragma unroll
            for (int e = 0; e < 4; ++e) a[u * 2][e]     += wv * bf2f((u16)vv[e]);
            #pragma unroll
            for (int e = 0; e < 4; ++e) a[u * 2 + 1][e] += wv * bf2f((u16)vv[e + 4]);
        }
    }

    const size_t ybase = ((size_t)b * 2048 + p * 128 + rloc) * 512 + h * 64 + dh;
    #pragma unroll
    for (int u = 0; u < 4; ++u) {
        s8v ov;
        #pragma unroll
        for (int e = 0; e < 4; ++e) ov[e]     = (short)f2bf(a[u * 2][e]);
        #pragma unroll
        for (int e = 0; e < 4; ++e) ov[e + 4] = (short)f2bf(a[u * 2 + 1][e]);
        *reinterpret_cast<s8v*>(YH + ybase + u * 8) = ov;
    }
}

// ---------------------------------------------------------------------------
// Kernel 3: output projection (transposed): C'[c][tok] = Wp^T . Y^T.
// Wp tile swizzled [128][64]; XCD-chunked map (same-mt consecutive per XCD).
// ---------------------------------------------------------------------------
__global__ __launch_bounds__(256)
void out_proj(const u16* __restrict__ YH, const float* __restrict__ Wp,
              const float* __restrict__ bp, float* __restrict__ out)
{
    __shared__ __align__(16) u16 Al[128 * 64];   // Wp^T tile, swizzled
    __shared__ u16 Bl[128][40];                  // Y tile (linear b128 write)

    const int bid = blockIdx.x;
    const int x = bid & 7, i = bid >> 3;         // 256 blocks
    const int mt = x + 8 * (i >> 2);
    const int ct = i & 3;
    const int c0 = ct << 7, m0 = mt << 7;

    const int tid = threadIdx.x, lane = tid & 63, w = tid >> 6;
    const int wr = (w >> 1) * 64, wc = (w & 1) * 64;
    const int cl = lane & 15, rl = lane >> 4;

    f4v acc[4][4] = {};

    const int lk = tid >> 3;
    const int lg = (tid & 7) * 16;
    const int br = tid >> 2;
    const int bq4 = (tid & 3) * 8;

    for (int k0 = 0; k0 < 512; k0 += 32) {
        {
            const float* g = Wp + (size_t)(k0 + lk) * 512 + c0 + lg;
            #pragma unroll
            for (int u = 0; u < 4; ++u) {
                f4v v = *reinterpret_cast<const f4v*>(g + u * 4);
                unsigned w0 = cvtpk(v[0], v[1]);
                unsigned w1 = cvtpk(v[2], v[3]);
                *(u16*)((char*)Al + swb(lg + u * 4 + 0, lk * 2)) = (u16)w0;
                *(u16*)((char*)Al + swb(lg + u * 4 + 1, lk * 2)) = (u16)(w0 >> 16);
                *(u16*)((char*)Al + swb(lg + u * 4 + 2, lk * 2)) = (u16)w1;
                *(u16*)((char*)Al + swb(lg + u * 4 + 3, lk * 2)) = (u16)(w1 >> 16);
            }
        }
        #pragma unroll
        for (int it = 0; it < 2; ++it) {
            const int row = br + it * 64;
            s8v v = *reinterpret_cast<const s8v*>(YH + (size_t)(m0 + row) * 512 + k0 + bq4);
            *reinterpret_cast<s8v*>(&Bl[row][bq4]) = v;
        }
        __syncthreads();
        s8v af[4], bfr[4];
        #pragma unroll
        for (int mi = 0; mi < 4; ++mi)
            af[mi] = *(const s8v*)((const char*)Al + swb(wr + mi * 16 + cl, rl * 16));
        #pragma unroll
        for (int ni = 0; ni < 4; ++ni)
            bfr[ni] = *reinterpret_cast<const s8v*>(&Bl[wc + ni * 16 + cl][rl * 8]);
        #pragma unroll
        for (int mi = 0; mi < 4; ++mi)
            #pragma unroll
            for (int ni = 0; ni < 4; ++ni)
                acc[mi][ni] = MFMA(af[mi], bfr[ni], acc[mi][ni]);
        __syncthreads();
    }

    #pragma unroll
    for (int mi = 0; mi < 4; ++mi)
        #pragma unroll
        for (int r = 0; r < 4; ++r) {
            const int c = c0 + wr + mi * 16 + rl * 4 + r;   // D row = cout
            const float bv = bp[c];
            #pragma unroll
            for (int ni = 0; ni < 4; ++ni) {
                const int tok = m0 + wc + ni * 16 + cl;     // D col = token
                const int bb = tok >> 11, t = tok & 2047;
                const int vv = t >> 8, hw = t & 255;
                out[(size_t)(vv * 4 + bb) * 131072 + (size_t)c * 256 + hw] =
                    acc[mi][ni][r] + bv;
            }
        }
}

// ---------------------------------------------------------------------------
extern "C" void kernel_launch(void* const* d_in, const int* in_sizes, int n_in,
                              void* d_out, int out_size, void* d_ws, size_t ws_size,
                              hipStream_t stream)
{
    const float* q   = (const float*)d_in[0];
    const float* kv  = (const float*)d_in[1];
    const float* Wq  = (const float*)d_in[2];
    const float* bq  = (const float*)d_in[3];
    const float* Wkv = (const float*)d_in[4];
    const float* bkv = (const float*)d_in[5];
    const float* Wp  = (const float*)d_in[6];
    const float* bp  = (const float*)d_in[7];
    float* out = (float*)d_out;

    u16* ws = (u16*)d_ws;
    u16* QH = ws;                    // [4][8][2048][64] bf16, prescaled Q
    u16* KH = QH + 4194304;          // [4][8][2048][64]
    u16* VT = KH + 4194304;          // [4][8][64][2048]
    u16* YH = VT + 4194304;          // [4][2048][512]
    u16* Opart = YH + 4194304;       // [1280][128][64] bf16 = 20 MB
    float* ML  = (float*)(Opart + 10485760);  // [1280][128][2] f32 = 1.3 MB

    hipLaunchKernelGGL(qkv_proj, dim3(768), dim3(256), 0, stream,
                       q, kv, Wq, bq, Wkv, bkv, QH, KH, VT);
    hipLaunchKernelGGL(attn_part, dim3(1280), dim3(256), 0, stream,
                       QH, KH, VT, Opart, ML);
    hipLaunchKernelGGL(attn_combine, dim3(512), dim3(256), 0, stream,
                       Opart, ML, YH);
    hipLaunchKernelGGL(out_proj, dim3(256), dim3(256), 0, stream, YH, Wp, bp, out);
}

// Round 9
// 125.525 us; speedup vs baseline: 1.7426x; 1.1495x over previous
//
#include <hip/hip_runtime.h>
#include <hip/hip_bf16.h>
#include <cmath>

typedef unsigned short u16;
typedef __attribute__((ext_vector_type(8))) short s8v;    // 8 x bf16 bits
typedef __attribute__((ext_vector_type(4))) float f4v;
typedef __attribute__((ext_vector_type(4))) unsigned short u16x4;

#define MFMA(a,b,c) __builtin_amdgcn_mfma_f32_16x16x32_bf16((a),(b),(c),0,0,0)

__device__ __forceinline__ float bf2f(u16 u) {
    union { float f; unsigned i; } x; x.i = ((unsigned)u) << 16; return x.f;
}
__device__ __forceinline__ u16 f2bf(float f) {
    union { float f; unsigned i; } x; x.f = f;
    unsigned r = x.i + 0x7FFFu + ((x.i >> 16) & 1u);
    return (u16)(r >> 16);
}
__device__ __forceinline__ unsigned cvtpk(float lo, float hi) {
    unsigned r;
    asm("v_cvt_pk_bf16_f32 %0, %1, %2" : "=v"(r) : "v"(lo), "v"(hi));
    return r;
}
__device__ __forceinline__ void gload_lds16(const void* g, void* l) {
    __builtin_amdgcn_global_load_lds(
        (const __attribute__((address_space(1))) unsigned int*)g,
        (__attribute__((address_space(3))) unsigned int*)l, 16, 0, 0);
}
// swizzled byte offset into a [128 rows][128 B] LDS tile; bijective per row,
// write side (rows 16 apart) and read side (rows consecutive) both conflict-free
__device__ __forceinline__ int swb(int row, int colb) {
    return row * 128 + (colb ^ ((((row >> 4) ^ row) & 7) << 4));
}

// chunks-per-qblock and per-p-tile prefix (512-key chunks, block-causal)
__constant__ int CPER[8]  = {1,1,2,2,3,3,4,4};
__constant__ int POFF[17] = {0,1,2,3,4,6,8,10,12,15,18,21,24,28,32,36,40};

// ---------------------------------------------------------------------------
// Kernel 1: fused QKV projection (f32 in -> bf16 MFMA -> bf16 out).
// Q output PRESCALED by 0.125*log2(e). Q,K: [b][h][T][d]; V: VT [b][h][d][T].
// XCD-chunked block map; LDS tiles XOR-swizzled (conflict-free).
// ---------------------------------------------------------------------------
__global__ __launch_bounds__(256)
void qkv_proj(const float* __restrict__ q, const float* __restrict__ kv,
              const float* __restrict__ Wq, const float* __restrict__ bq,
              const float* __restrict__ Wkv, const float* __restrict__ bkv,
              u16* __restrict__ QH, u16* __restrict__ KH, u16* __restrict__ VT)
{
    __shared__ __align__(16) u16 Al[128 * 64];
    __shared__ __align__(16) u16 Bl[128 * 64];

    const int bid = blockIdx.x;
    const int x = bid & 7, i = bid >> 3;     // XCD-chunked: same-mt consecutive
    const int mt = x + 8 * (i / 12);
    const int nt = i % 12;
    const int m0 = mt << 7, n0 = nt << 7;

    const int tid  = threadIdx.x;
    const int lane = tid & 63;
    const int w    = tid >> 6;
    const int wr = (w >> 1) * 64, wc = (w & 1) * 64;
    const int cl = lane & 15, rl = lane >> 4;

    const int bb  = m0 >> 11;
    const int t0  = m0 & 2047;
    const int vv  = t0 >> 8;
    const int hw0 = t0 & 255;

    const float* Abase = ((nt < 4) ? q : kv) + (size_t)(vv * 4 + bb) * 131072 + hw0;

    const float* W; const float* bias; int NW, wn0, dn0; u16* dst;
    if (nt < 4)      { W = Wq;  bias = bq;  NW = 512;  wn0 = n0;       dn0 = n0;        dst = QH; }
    else if (nt < 8) { W = Wkv; bias = bkv; NW = 1024; wn0 = n0 - 512; dn0 = n0 - 512;  dst = KH; }
    else             { W = Wkv; bias = bkv; NW = 1024; wn0 = n0 - 512; dn0 = n0 - 1024; dst = VT; }

    const float oscale = (nt < 4) ? 0.18033688011f : 1.0f;  // 0.125*log2(e)

    f4v acc[4][4] = {};

    const int lk = tid >> 3;          // k within tile: 0..31
    const int lg = (tid & 7) * 16;    // m/n group base

    for (int k0 = 0; k0 < 512; k0 += 32) {
        {
            const float* g = Abase + (size_t)(k0 + lk) * 256 + lg;
            #pragma unroll
            for (int u = 0; u < 4; ++u) {
                f4v v = *reinterpret_cast<const f4v*>(g + u * 4);
                unsigned w0 = cvtpk(v[0], v[1]);
                unsigned w1 = cvtpk(v[2], v[3]);
                *(u16*)((char*)Al + swb(lg + u * 4 + 0, lk * 2)) = (u16)w0;
                *(u16*)((char*)Al + swb(lg + u * 4 + 1, lk * 2)) = (u16)(w0 >> 16);
                *(u16*)((char*)Al + swb(lg + u * 4 + 2, lk * 2)) = (u16)w1;
                *(u16*)((char*)Al + swb(lg + u * 4 + 3, lk * 2)) = (u16)(w1 >> 16);
            }
        }
        {
            const float* g = W + (size_t)(k0 + lk) * NW + wn0 + lg;
            #pragma unroll
            for (int u = 0; u < 4; ++u) {
                f4v v = *reinterpret_cast<const f4v*>(g + u * 4);
                unsigned w0 = cvtpk(v[0], v[1]);
                unsigned w1 = cvtpk(v[2], v[3]);
                *(u16*)((char*)Bl + swb(lg + u * 4 + 0, lk * 2)) = (u16)w0;
                *(u16*)((char*)Bl + swb(lg + u * 4 + 1, lk * 2)) = (u16)(w0 >> 16);
                *(u16*)((char*)Bl + swb(lg + u * 4 + 2, lk * 2)) = (u16)w1;
                *(u16*)((char*)Bl + swb(lg + u * 4 + 3, lk * 2)) = (u16)(w1 >> 16);
            }
        }
        __syncthreads();
        s8v af[4], bf[4];
        #pragma unroll
        for (int mi = 0; mi < 4; ++mi)
            af[mi] = *(const s8v*)((const char*)Al + swb(wr + mi * 16 + cl, rl * 16));
        #pragma unroll
        for (int ni = 0; ni < 4; ++ni)
            bf[ni] = *(const s8v*)((const char*)Bl + swb(wc + ni * 16 + cl, rl * 16));
        #pragma unroll
        for (int mi = 0; mi < 4; ++mi)
            #pragma unroll
            for (int ni = 0; ni < 4; ++ni)
                acc[mi][ni] = MFMA(af[mi], bf[ni], acc[mi][ni]);
        __syncthreads();
    }

    if (nt < 8) {
        #pragma unroll
        for (int ni = 0; ni < 4; ++ni) {
            const int nl   = wc + ni * 16 + cl;
            const float bv = bias[wn0 + nl];
            const int cout = dn0 + nl;
            const int hh = cout >> 6, dd = cout & 63;
            const size_t obase = ((size_t)(bb * 8 + hh) * 2048) * 64 + dd;
            #pragma unroll
            for (int mi = 0; mi < 4; ++mi)
                #pragma unroll
                for (int r = 0; r < 4; ++r) {
                    const int m = m0 + wr + mi * 16 + rl * 4 + r;
                    const int t = m & 2047;
                    dst[obase + (size_t)t * 64] = f2bf((acc[mi][ni][r] + bv) * oscale);
                }
        }
    } else {
        #pragma unroll
        for (int ni = 0; ni < 4; ++ni) {
            const int nl   = wc + ni * 16 + cl;
            const float bv = bias[wn0 + nl];
            const int cout = dn0 + nl;
            const int hh = cout >> 6, dd = cout & 63;
            const size_t obase = ((size_t)(bb * 8 + hh) * 64 + dd) * 2048;
            #pragma unroll
            for (int mi = 0; mi < 4; ++mi) {
                const int m = m0 + wr + mi * 16 + rl * 4;
                const int t = m & 2047;
                u16x4 pk;
                #pragma unroll
                for (int r = 0; r < 4; ++r) pk[r] = f2bf(acc[mi][ni][r] + bv);
                *reinterpret_cast<u16x4*>(dst + obase + t) = pk;
            }
        }
    }
}

// ---------------------------------------------------------------------------
// Kernel 2a: attention partials. WG = (bh, 128-row q-tile p, 512-key chunk c).
// Fixed-max softmax (scores bounded -> P = exp2(s) directly, no max tracking,
// no rescale, no in-loop shuffles). KVBLK=64, LDS 41KB -> 3 blocks/CU.
// K/V staged via global_load_lds with pre-swizzled source (conflict-free).
// Heavy chunks dispatched first.
// ---------------------------------------------------------------------------
__global__ __launch_bounds__(256, 3)
void attn_part(const u16* __restrict__ QH, const u16* __restrict__ KH,
               const u16* __restrict__ VT,
               u16* __restrict__ Opart, float* __restrict__ ML)
{
    __shared__ __align__(16) u16 Kl[2][4096];  // [64 key][64 d], byte^=(key&7)<<4
    __shared__ __align__(16) u16 Vl[2][4096];  // [64 d][64 key], byte^=(d&7)<<4
    __shared__ u16 Pl[4][32][36];              // per-wave 32-key P slice

    const int wg = blockIdx.x;
    const int bh = wg & 31;
    const int s  = 39 - (wg >> 5);        // heavy (512-key) chunks first
    int p = 0;
    #pragma unroll
    for (int i = 0; i < 15; ++i) p += (s >= POFF[i + 1]) ? 1 : 0;
    const int c  = s - POFF[p];
    const int qb = p >> 1;
    const int kstart = c * 512;
    const int nk = min(512, (qb + 1) * 256 - kstart);
    const int nt64 = nk >> 6;             // 4 or 8 key tiles of 64

    const int tid = threadIdx.x, lane = tid & 63, w = tid >> 6;
    const int cl = lane & 15, rl = lane >> 4;

    const u16* Qb = QH + (size_t)bh * 131072;
    const u16* Kb = KH + (size_t)bh * 131072;
    const u16* Vb = VT + (size_t)bh * 131072;

    const int qrow0 = p * 128 + w * 32;

    s8v qf[2][2];
    #pragma unroll
    for (int mi = 0; mi < 2; ++mi)
        #pragma unroll
        for (int kf = 0; kf < 2; ++kf)
            qf[mi][kf] = *reinterpret_cast<const s8v*>(
                Qb + (size_t)(qrow0 + mi * 16 + cl) * 64 + kf * 32 + rl * 8);

    // per-thread pre-swizzled source offsets (slot f = w*128 + i*64 + lane)
    unsigned kofs[2], vofs[2];
    #pragma unroll
    for (int i = 0; i < 2; ++i) {
        const int f = w * 128 + i * 64 + lane;
        const int row = f >> 3;
        kofs[i] = row * 128 + (((f & 7) * 16) ^ ((row & 7) << 4));
        vofs[i] = row * 4096 + (((f & 7) * 16) ^ ((row & 7) << 4));
    }

#define ISSUE(bufi, kb0_) do {                                               \
        const char* kG = (const char*)Kb + (size_t)(kb0_) * 128;             \
        const char* vG = (const char*)Vb + (size_t)(kb0_) * 2;               \
        char* kL = (char*)&Kl[bufi][0] + w * 2048;                           \
        char* vL = (char*)&Vl[bufi][0] + w * 2048;                           \
        _Pragma("unroll")                                                    \
        for (int i_ = 0; i_ < 2; ++i_) {                                     \
            gload_lds16(kG + kofs[i_], kL + i_ * 1024);                      \
            gload_lds16(vG + vofs[i_], vL + i_ * 1024);                      \
        }                                                                    \
    } while (0)

    f4v o[2][4] = {};
    float lp[8] = {0.f, 0.f, 0.f, 0.f, 0.f, 0.f, 0.f, 0.f};

    ISSUE(0, kstart);

    for (int kt = 0; kt < nt64; ++kt) {
        asm volatile("s_waitcnt vmcnt(0)" ::: "memory");
        __builtin_amdgcn_sched_barrier(0);
        __syncthreads();
        if (kt + 1 < nt64) ISSUE((kt + 1) & 1, kstart + (kt + 1) * 64);

        const char* Kbase = (const char*)&Kl[kt & 1][0];
        const char* Vbase = (const char*)&Vl[kt & 1][0];

        // S = Q K^T (swizzled LDS reads)
        f4v sc[2][4] = {};
        #pragma unroll
        for (int ni = 0; ni < 4; ++ni)
            #pragma unroll
            for (int kf = 0; kf < 2; ++kf) {
                const int row = ni * 16 + cl;
                s8v kfr = *reinterpret_cast<const s8v*>(
                    Kbase + row * 128 + ((kf * 64 + rl * 16) ^ ((row & 7) << 4)));
                sc[0][ni] = MFMA(qf[0][kf], kfr, sc[0][ni]);
                sc[1][ni] = MFMA(qf[1][kf], kfr, sc[1][ni]);
            }

        // fixed-max softmax: P = exp2(s) directly (s bounded, Q prescaled)
        #pragma unroll
        for (int mi = 0; mi < 2; ++mi)
            #pragma unroll
            for (int ni = 0; ni < 4; ++ni)
                #pragma unroll
                for (int r = 0; r < 4; ++r)
                    sc[mi][ni][r] = exp2f(sc[mi][ni][r]);
        #pragma unroll
        for (int mi = 0; mi < 2; ++mi)
            #pragma unroll
            for (int r = 0; r < 4; ++r)
                lp[mi * 4 + r] += sc[mi][0][r] + sc[mi][1][r]
                                + sc[mi][2][r] + sc[mi][3][r];

        // PV in two 32-key windows through per-wave LDS
        #pragma unroll
        for (int kw = 0; kw < 2; ++kw) {
            #pragma unroll
            for (int mi = 0; mi < 2; ++mi)
                #pragma unroll
                for (int jj = 0; jj < 2; ++jj) {
                    const int ni = kw * 2 + jj;
                    const unsigned w0 = cvtpk(sc[mi][ni][0], sc[mi][ni][1]);
                    const unsigned w1 = cvtpk(sc[mi][ni][2], sc[mi][ni][3]);
                    const int col = jj * 16 + cl;
                    Pl[w][mi * 16 + rl * 4 + 0][col] = (u16)w0;
                    Pl[w][mi * 16 + rl * 4 + 1][col] = (u16)(w0 >> 16);
                    Pl[w][mi * 16 + rl * 4 + 2][col] = (u16)w1;
                    Pl[w][mi * 16 + rl * 4 + 3][col] = (u16)(w1 >> 16);
                }
            s8v pf0 = *reinterpret_cast<const s8v*>(&Pl[w][cl][rl * 8]);
            s8v pf1 = *reinterpret_cast<const s8v*>(&Pl[w][16 + cl][rl * 8]);
            #pragma unroll
            for (int di = 0; di < 4; ++di) {
                const int row = di * 16 + cl;
                s8v vf = *reinterpret_cast<const s8v*>(
                    Vbase + row * 128 + ((kw * 64 + rl * 16) ^ ((row & 7) << 4)));
                o[0][di] = MFMA(pf0, vf, o[0][di]);
                o[1][di] = MFMA(pf1, vf, o[1][di]);
            }
        }
    }
#undef ISSUE

    // write partial: Ohat = O/l (bf16), l (f32)
    const int slot = bh * 40 + POFF[p] + c;
    #pragma unroll
    for (int mi = 0; mi < 2; ++mi)
        #pragma unroll
        for (int r = 0; r < 4; ++r) {
            const int idx = mi * 4 + r;
            float ls = lp[idx];
            ls += __shfl_xor(ls, 1);
            ls += __shfl_xor(ls, 2);
            ls += __shfl_xor(ls, 4);
            ls += __shfl_xor(ls, 8);
            const float inv = 1.f / ls;
            const int rloc = w * 32 + mi * 16 + rl * 4 + r;
            if (cl == 0) ML[(size_t)slot * 128 + rloc] = ls;
            #pragma unroll
            for (int di = 0; di < 4; ++di)
                Opart[(size_t)slot * 8192 + rloc * 64 + di * 16 + cl] =
                    f2bf(o[mi][di][r] * inv);
        }
}

// ---------------------------------------------------------------------------
// Kernel 2b: combine partials -> YH [b][t][c] bf16. weights = l_c / sum l_c.
// ---------------------------------------------------------------------------
__global__ __launch_bounds__(256)
void attn_combine(const u16* __restrict__ Opart, const float* __restrict__ ML,
                  u16* __restrict__ YH)
{
    const int wg = blockIdx.x;
    const int bh = wg & 31;
    const int p  = wg >> 5;
    const int b = bh >> 3, h = bh & 7;
    const int nc = CPER[p >> 1];
    const int sb = bh * 40 + POFF[p];

    const int t = threadIdx.x;
    const int rloc = t >> 1;
    const int dh = (t & 1) * 32;

    float lc[4], L = 0.f;
    for (int c = 0; c < nc; ++c) {
        lc[c] = ML[(size_t)(sb + c) * 128 + rloc];
        L += lc[c];
    }
    const float invL = 1.f / L;
    float wgt[4];
    for (int c = 0; c < nc; ++c) wgt[c] = lc[c] * invL;

    f4v a[8] = {};
    for (int c = 0; c < nc; ++c) {
        const float wv = wgt[c];
        #pragma unroll
        for (int u = 0; u < 4; ++u) {
            s8v vv = *reinterpret_cast<const s8v*>(
                &Opart[(size_t)(sb + c) * 8192 + rloc * 64 + dh + u * 8]);
            #pragma unroll
            for (int e = 0; e < 4; ++e) a[u * 2][e]     += wv * bf2f((u16)vv[e]);
            #pragma unroll
            for (int e = 0; e < 4; ++e) a[u * 2 + 1][e] += wv * bf2f((u16)vv[e + 4]);
        }
    }

    const size_t ybase = ((size_t)b * 2048 + p * 128 + rloc) * 512 + h * 64 + dh;
    #pragma unroll
    for (int u = 0; u < 4; ++u) {
        s8v ov;
        #pragma unroll
        for (int e = 0; e < 4; ++e) ov[e]     = (short)f2bf(a[u * 2][e]);
        #pragma unroll
        for (int e = 0; e < 4; ++e) ov[e + 4] = (short)f2bf(a[u * 2 + 1][e]);
        *reinterpret_cast<s8v*>(YH + ybase + u * 8) = ov;
    }
}

// ---------------------------------------------------------------------------
// Kernel 3: output projection (transposed): C'[c][tok] = Wp^T . Y^T.
// Wp tile swizzled; XCD-chunked map.
// ---------------------------------------------------------------------------
__global__ __launch_bounds__(256)
void out_proj(const u16* __restrict__ YH, const float* __restrict__ Wp,
              const float* __restrict__ bp, float* __restrict__ out)
{
    __shared__ __align__(16) u16 Al[128 * 64];   // Wp^T tile, swizzled
    __shared__ u16 Bl[128][40];                  // Y tile (linear b128 write)

    const int bid = blockIdx.x;
    const int x = bid & 7, i = bid >> 3;         // 256 blocks
    const int mt = x + 8 * (i >> 2);
    const int ct = i & 3;
    const int c0 = ct << 7, m0 = mt << 7;

    const int tid = threadIdx.x, lane = tid & 63, w = tid >> 6;
    const int wr = (w >> 1) * 64, wc = (w & 1) * 64;
    const int cl = lane & 15, rl = lane >> 4;

    f4v acc[4][4] = {};

    const int lk = tid >> 3;
    const int lg = (tid & 7) * 16;
    const int br = tid >> 2;
    const int bq4 = (tid & 3) * 8;

    for (int k0 = 0; k0 < 512; k0 += 32) {
        {
            const float* g = Wp + (size_t)(k0 + lk) * 512 + c0 + lg;
            #pragma unroll
            for (int u = 0; u < 4; ++u) {
                f4v v = *reinterpret_cast<const f4v*>(g + u * 4);
                unsigned w0 = cvtpk(v[0], v[1]);
                unsigned w1 = cvtpk(v[2], v[3]);
                *(u16*)((char*)Al + swb(lg + u * 4 + 0, lk * 2)) = (u16)w0;
                *(u16*)((char*)Al + swb(lg + u * 4 + 1, lk * 2)) = (u16)(w0 >> 16);
                *(u16*)((char*)Al + swb(lg + u * 4 + 2, lk * 2)) = (u16)w1;
                *(u16*)((char*)Al + swb(lg + u * 4 + 3, lk * 2)) = (u16)(w1 >> 16);
            }
        }
        #pragma unroll
        for (int it = 0; it < 2; ++it) {
            const int row = br + it * 64;
            s8v v = *reinterpret_cast<const s8v*>(YH + (size_t)(m0 + row) * 512 + k0 + bq4);
            *reinterpret_cast<s8v*>(&Bl[row][bq4]) = v;
        }
        __syncthreads();
        s8v af[4], bfr[4];
        #pragma unroll
        for (int mi = 0; mi < 4; ++mi)
            af[mi] = *(const s8v*)((const char*)Al + swb(wr + mi * 16 + cl, rl * 16));
        #pragma unroll
        for (int ni = 0; ni < 4; ++ni)
            bfr[ni] = *reinterpret_cast<const s8v*>(&Bl[wc + ni * 16 + cl][rl * 8]);
        #pragma unroll
        for (int mi = 0; mi < 4; ++mi)
            #pragma unroll
            for (int ni = 0; ni < 4; ++ni)
                acc[mi][ni] = MFMA(af[mi], bfr[ni], acc[mi][ni]);
        __syncthreads();
    }

    #pragma unroll
    for (int mi = 0; mi < 4; ++mi)
        #pragma unroll
        for (int r = 0; r < 4; ++r) {
            const int c = c0 + wr + mi * 16 + rl * 4 + r;   // D row = cout
            const float bv = bp[c];
            #pragma unroll
            for (int ni = 0; ni < 4; ++ni) {
                const int tok = m0 + wc + ni * 16 + cl;     // D col = token
                const int bb = tok >> 11, t = tok & 2047;
                const int vv = t >> 8, hw = t & 255;
                out[(size_t)(vv * 4 + bb) * 131072 + (size_t)c * 256 + hw] =
                    acc[mi][ni][r] + bv;
            }
        }
}

// ---------------------------------------------------------------------------
extern "C" void kernel_launch(void* const* d_in, const int* in_sizes, int n_in,
                              void* d_out, int out_size, void* d_ws, size_t ws_size,
                              hipStream_t stream)
{
    const float* q   = (const float*)d_in[0];
    const float* kv  = (const float*)d_in[1];
    const float* Wq  = (const float*)d_in[2];
    const float* bq  = (const float*)d_in[3];
    const float* Wkv = (const float*)d_in[4];
    const float* bkv = (const float*)d_in[5];
    const float* Wp  = (const float*)d_in[6];
    const float* bp  = (const float*)d_in[7];
    float* out = (float*)d_out;

    u16* ws = (u16*)d_ws;
    u16* QH = ws;                    // [4][8][2048][64] bf16, prescaled Q
    u16* KH = QH + 4194304;          // [4][8][2048][64]
    u16* VT = KH + 4194304;          // [4][8][64][2048]
    u16* YH = VT + 4194304;          // [4][2048][512]
    u16* Opart = YH + 4194304;       // [1280][128][64] bf16 = 20 MB
    float* ML  = (float*)(Opart + 10485760);  // [1280][128] f32 = 0.66 MB

    hipLaunchKernelGGL(qkv_proj, dim3(768), dim3(256), 0, stream,
                       q, kv, Wq, bq, Wkv, bkv, QH, KH, VT);
    hipLaunchKernelGGL(attn_part, dim3(1280), dim3(256), 0, stream,
                       QH, KH, VT, Opart, ML);
    hipLaunchKernelGGL(attn_combine, dim3(512), dim3(256), 0, stream,
                       Opart, ML, YH);
    hipLaunchKernelGGL(out_proj, dim3(256), dim3(256), 0, stream, YH, Wp, bp, out);
}

// Round 10
// 110.247 us; speedup vs baseline: 1.9841x; 1.1386x over previous
//
#include <hip/hip_runtime.h>
#include <hip/hip_bf16.h>
#include <cmath>

typedef unsigned short u16;
typedef __attribute__((ext_vector_type(8))) short s8v;    // 8 x bf16 bits
typedef __attribute__((ext_vector_type(4))) float f4v;
typedef __attribute__((ext_vector_type(4))) unsigned short u16x4;

#define MFMA(a,b,c) __builtin_amdgcn_mfma_f32_16x16x32_bf16((a),(b),(c),0,0,0)

__device__ __forceinline__ float bf2f(u16 u) {
    union { float f; unsigned i; } x; x.i = ((unsigned)u) << 16; return x.f;
}
__device__ __forceinline__ u16 f2bf(float f) {
    union { float f; unsigned i; } x; x.f = f;
    unsigned r = x.i + 0x7FFFu + ((x.i >> 16) & 1u);
    return (u16)(r >> 16);
}
__device__ __forceinline__ unsigned cvtpk(float lo, float hi) {
    unsigned r;
    asm("v_cvt_pk_bf16_f32 %0, %1, %2" : "=v"(r) : "v"(lo), "v"(hi));
    return r;
}
__device__ __forceinline__ void gload_lds16(const void* g, void* l) {
    __builtin_amdgcn_global_load_lds(
        (const __attribute__((address_space(1))) unsigned int*)g,
        (__attribute__((address_space(3))) unsigned int*)l, 16, 0, 0);
}
// swizzled byte offset into a [128 rows][128 B] LDS tile; bijective per row,
// write side (rows 16 apart) and read side (rows consecutive) both conflict-free
__device__ __forceinline__ int swb(int row, int colb) {
    return row * 128 + (colb ^ ((((row >> 4) ^ row) & 7) << 4));
}

// chunks-per-qblock and per-p-tile prefix (512-key chunks, block-causal)
__constant__ int CPER[8]  = {1,1,2,2,3,3,4,4};
__constant__ int POFF[17] = {0,1,2,3,4,6,8,10,12,15,18,21,24,28,32,36,40};

// ---------------------------------------------------------------------------
// Kernel 1: fused QKV projection (f32 in -> bf16 MFMA -> bf16 out).
// Q output PRESCALED by 0.125*log2(e). Q,K: [b][h][T][d]; V: VT [b][h][d][T].
// XCD-chunked block map; swizzled LDS; T14 pipeline: write cur -> barrier ->
// load next (latency hidden under MFMA) -> MFMA -> barrier.
// ---------------------------------------------------------------------------
__global__ __launch_bounds__(256)
void qkv_proj(const float* __restrict__ q, const float* __restrict__ kv,
              const float* __restrict__ Wq, const float* __restrict__ bq,
              const float* __restrict__ Wkv, const float* __restrict__ bkv,
              u16* __restrict__ QH, u16* __restrict__ KH, u16* __restrict__ VT)
{
    __shared__ __align__(16) u16 Al[128 * 64];
    __shared__ __align__(16) u16 Bl[128 * 64];

    const int bid = blockIdx.x;
    const int x = bid & 7, i = bid >> 3;     // XCD-chunked: same-mt consecutive
    const int mt = x + 8 * (i / 12);
    const int nt = i % 12;
    const int m0 = mt << 7, n0 = nt << 7;

    const int tid  = threadIdx.x;
    const int lane = tid & 63;
    const int w    = tid >> 6;
    const int wr = (w >> 1) * 64, wc = (w & 1) * 64;
    const int cl = lane & 15, rl = lane >> 4;

    const int bb  = m0 >> 11;
    const int t0  = m0 & 2047;
    const int vv  = t0 >> 8;
    const int hw0 = t0 & 255;

    const float* Abase = ((nt < 4) ? q : kv) + (size_t)(vv * 4 + bb) * 131072 + hw0;

    const float* W; const float* bias; int NW, wn0, dn0; u16* dst;
    if (nt < 4)      { W = Wq;  bias = bq;  NW = 512;  wn0 = n0;       dn0 = n0;        dst = QH; }
    else if (nt < 8) { W = Wkv; bias = bkv; NW = 1024; wn0 = n0 - 512; dn0 = n0 - 512;  dst = KH; }
    else             { W = Wkv; bias = bkv; NW = 1024; wn0 = n0 - 512; dn0 = n0 - 1024; dst = VT; }

    const float oscale = (nt < 4) ? 0.18033688011f : 1.0f;  // 0.125*log2(e)

    f4v acc[4][4] = {};
    f4v sa[4], sb[4];                 // staging regs (single set, WAR-ordered)

    const int lk = tid >> 3;          // k within tile: 0..31
    const int lg = (tid & 7) * 16;    // m/n group base

#define QKV_LOAD(k0_) do {                                                   \
        const float* gA = Abase + (size_t)((k0_) + lk) * 256 + lg;           \
        const float* gB = W + (size_t)((k0_) + lk) * NW + wn0 + lg;          \
        _Pragma("unroll")                                                    \
        for (int u = 0; u < 4; ++u) {                                        \
            sa[u] = *reinterpret_cast<const f4v*>(gA + u * 4);               \
            sb[u] = *reinterpret_cast<const f4v*>(gB + u * 4);               \
        }                                                                    \
    } while (0)

    QKV_LOAD(0);

    for (int k0 = 0; k0 < 512; k0 += 32) {
        #pragma unroll
        for (int u = 0; u < 4; ++u) {
            unsigned a0 = cvtpk(sa[u][0], sa[u][1]);
            unsigned a1 = cvtpk(sa[u][2], sa[u][3]);
            *(u16*)((char*)Al + swb(lg + u * 4 + 0, lk * 2)) = (u16)a0;
            *(u16*)((char*)Al + swb(lg + u * 4 + 1, lk * 2)) = (u16)(a0 >> 16);
            *(u16*)((char*)Al + swb(lg + u * 4 + 2, lk * 2)) = (u16)a1;
            *(u16*)((char*)Al + swb(lg + u * 4 + 3, lk * 2)) = (u16)(a1 >> 16);
            unsigned b0 = cvtpk(sb[u][0], sb[u][1]);
            unsigned b1 = cvtpk(sb[u][2], sb[u][3]);
            *(u16*)((char*)Bl + swb(lg + u * 4 + 0, lk * 2)) = (u16)b0;
            *(u16*)((char*)Bl + swb(lg + u * 4 + 1, lk * 2)) = (u16)(b0 >> 16);
            *(u16*)((char*)Bl + swb(lg + u * 4 + 2, lk * 2)) = (u16)b1;
            *(u16*)((char*)Bl + swb(lg + u * 4 + 3, lk * 2)) = (u16)(b1 >> 16);
        }
        __syncthreads();
        if (k0 + 32 < 512) QKV_LOAD(k0 + 32);   // latency hides under MFMA

        s8v af[4], bf[4];
        #pragma unroll
        for (int mi = 0; mi < 4; ++mi)
            af[mi] = *(const s8v*)((const char*)Al + swb(wr + mi * 16 + cl, rl * 16));
        #pragma unroll
        for (int ni = 0; ni < 4; ++ni)
            bf[ni] = *(const s8v*)((const char*)Bl + swb(wc + ni * 16 + cl, rl * 16));
        #pragma unroll
        for (int mi = 0; mi < 4; ++mi)
            #pragma unroll
            for (int ni = 0; ni < 4; ++ni)
                acc[mi][ni] = MFMA(af[mi], bf[ni], acc[mi][ni]);
        __syncthreads();
    }
#undef QKV_LOAD

    if (nt < 8) {
        #pragma unroll
        for (int ni = 0; ni < 4; ++ni) {
            const int nl   = wc + ni * 16 + cl;
            const float bv = bias[wn0 + nl];
            const int cout = dn0 + nl;
            const int hh = cout >> 6, dd = cout & 63;
            const size_t obase = ((size_t)(bb * 8 + hh) * 2048) * 64 + dd;
            #pragma unroll
            for (int mi = 0; mi < 4; ++mi)
                #pragma unroll
                for (int r = 0; r < 4; ++r) {
                    const int m = m0 + wr + mi * 16 + rl * 4 + r;
                    const int t = m & 2047;
                    dst[obase + (size_t)t * 64] = f2bf((acc[mi][ni][r] + bv) * oscale);
                }
        }
    } else {
        #pragma unroll
        for (int ni = 0; ni < 4; ++ni) {
            const int nl   = wc + ni * 16 + cl;
            const float bv = bias[wn0 + nl];
            const int cout = dn0 + nl;
            const int hh = cout >> 6, dd = cout & 63;
            const size_t obase = ((size_t)(bb * 8 + hh) * 64 + dd) * 2048;
            #pragma unroll
            for (int mi = 0; mi < 4; ++mi) {
                const int m = m0 + wr + mi * 16 + rl * 4;
                const int t = m & 2047;
                u16x4 pk;
                #pragma unroll
                for (int r = 0; r < 4; ++r) pk[r] = f2bf(acc[mi][ni][r] + bv);
                *reinterpret_cast<u16x4*>(dst + obase + t) = pk;
            }
        }
    }
}

// ---------------------------------------------------------------------------
// Kernel 2a: attention partials. WG = (bh, 128-row q-tile p, 512-key chunk c).
// Fixed-max softmax; KVBLK=64; gload_lds with pre-swizzled source.
// ---------------------------------------------------------------------------
__global__ __launch_bounds__(256, 3)
void attn_part(const u16* __restrict__ QH, const u16* __restrict__ KH,
               const u16* __restrict__ VT,
               u16* __restrict__ Opart, float* __restrict__ ML)
{
    __shared__ __align__(16) u16 Kl[2][4096];  // [64 key][64 d], byte^=(key&7)<<4
    __shared__ __align__(16) u16 Vl[2][4096];  // [64 d][64 key], byte^=(d&7)<<4
    __shared__ u16 Pl[4][32][36];              // per-wave 32-key P slice

    const int wg = blockIdx.x;
    const int bh = wg & 31;
    const int s  = 39 - (wg >> 5);        // heavy (512-key) chunks first
    int p = 0;
    #pragma unroll
    for (int i = 0; i < 15; ++i) p += (s >= POFF[i + 1]) ? 1 : 0;
    const int c  = s - POFF[p];
    const int qb = p >> 1;
    const int kstart = c * 512;
    const int nk = min(512, (qb + 1) * 256 - kstart);
    const int nt64 = nk >> 6;             // 4 or 8 key tiles of 64

    const int tid = threadIdx.x, lane = tid & 63, w = tid >> 6;
    const int cl = lane & 15, rl = lane >> 4;

    const u16* Qb = QH + (size_t)bh * 131072;
    const u16* Kb = KH + (size_t)bh * 131072;
    const u16* Vb = VT + (size_t)bh * 131072;

    const int qrow0 = p * 128 + w * 32;

    s8v qf[2][2];
    #pragma unroll
    for (int mi = 0; mi < 2; ++mi)
        #pragma unroll
        for (int kf = 0; kf < 2; ++kf)
            qf[mi][kf] = *reinterpret_cast<const s8v*>(
                Qb + (size_t)(qrow0 + mi * 16 + cl) * 64 + kf * 32 + rl * 8);

    // per-thread pre-swizzled source offsets (slot f = w*128 + i*64 + lane)
    unsigned kofs[2], vofs[2];
    #pragma unroll
    for (int i = 0; i < 2; ++i) {
        const int f = w * 128 + i * 64 + lane;
        const int row = f >> 3;
        kofs[i] = row * 128 + (((f & 7) * 16) ^ ((row & 7) << 4));
        vofs[i] = row * 4096 + (((f & 7) * 16) ^ ((row & 7) << 4));
    }

#define ISSUE(bufi, kb0_) do {                                               \
        const char* kG = (const char*)Kb + (size_t)(kb0_) * 128;             \
        const char* vG = (const char*)Vb + (size_t)(kb0_) * 2;               \
        char* kL = (char*)&Kl[bufi][0] + w * 2048;                           \
        char* vL = (char*)&Vl[bufi][0] + w * 2048;                           \
        _Pragma("unroll")                                                    \
        for (int i_ = 0; i_ < 2; ++i_) {                                     \
            gload_lds16(kG + kofs[i_], kL + i_ * 1024);                      \
            gload_lds16(vG + vofs[i_], vL + i_ * 1024);                      \
        }                                                                    \
    } while (0)

    f4v o[2][4] = {};
    float lp[8] = {0.f, 0.f, 0.f, 0.f, 0.f, 0.f, 0.f, 0.f};

    ISSUE(0, kstart);

    for (int kt = 0; kt < nt64; ++kt) {
        asm volatile("s_waitcnt vmcnt(0)" ::: "memory");
        __builtin_amdgcn_sched_barrier(0);
        __syncthreads();
        if (kt + 1 < nt64) ISSUE((kt + 1) & 1, kstart + (kt + 1) * 64);

        const char* Kbase = (const char*)&Kl[kt & 1][0];
        const char* Vbase = (const char*)&Vl[kt & 1][0];

        // S = Q K^T (swizzled LDS reads)
        f4v sc[2][4] = {};
        #pragma unroll
        for (int ni = 0; ni < 4; ++ni)
            #pragma unroll
            for (int kf = 0; kf < 2; ++kf) {
                const int row = ni * 16 + cl;
                s8v kfr = *reinterpret_cast<const s8v*>(
                    Kbase + row * 128 + ((kf * 64 + rl * 16) ^ ((row & 7) << 4)));
                sc[0][ni] = MFMA(qf[0][kf], kfr, sc[0][ni]);
                sc[1][ni] = MFMA(qf[1][kf], kfr, sc[1][ni]);
            }

        // fixed-max softmax: P = exp2(s) directly (s bounded, Q prescaled)
        #pragma unroll
        for (int mi = 0; mi < 2; ++mi)
            #pragma unroll
            for (int ni = 0; ni < 4; ++ni)
                #pragma unroll
                for (int r = 0; r < 4; ++r)
                    sc[mi][ni][r] = exp2f(sc[mi][ni][r]);
        #pragma unroll
        for (int mi = 0; mi < 2; ++mi)
            #pragma unroll
            for (int r = 0; r < 4; ++r)
                lp[mi * 4 + r] += sc[mi][0][r] + sc[mi][1][r]
                                + sc[mi][2][r] + sc[mi][3][r];

        // PV in two 32-key windows through per-wave LDS
        #pragma unroll
        for (int kw = 0; kw < 2; ++kw) {
            #pragma unroll
            for (int mi = 0; mi < 2; ++mi)
                #pragma unroll
                for (int jj = 0; jj < 2; ++jj) {
                    const int ni = kw * 2 + jj;
                    const unsigned w0 = cvtpk(sc[mi][ni][0], sc[mi][ni][1]);
                    const unsigned w1 = cvtpk(sc[mi][ni][2], sc[mi][ni][3]);
                    const int col = jj * 16 + cl;
                    Pl[w][mi * 16 + rl * 4 + 0][col] = (u16)w0;
                    Pl[w][mi * 16 + rl * 4 + 1][col] = (u16)(w0 >> 16);
                    Pl[w][mi * 16 + rl * 4 + 2][col] = (u16)w1;
                    Pl[w][mi * 16 + rl * 4 + 3][col] = (u16)(w1 >> 16);
                }
            s8v pf0 = *reinterpret_cast<const s8v*>(&Pl[w][cl][rl * 8]);
            s8v pf1 = *reinterpret_cast<const s8v*>(&Pl[w][16 + cl][rl * 8]);
            #pragma unroll
            for (int di = 0; di < 4; ++di) {
                const int row = di * 16 + cl;
                s8v vf = *reinterpret_cast<const s8v*>(
                    Vbase + row * 128 + ((kw * 64 + rl * 16) ^ ((row & 7) << 4)));
                o[0][di] = MFMA(pf0, vf, o[0][di]);
                o[1][di] = MFMA(pf1, vf, o[1][di]);
            }
        }
    }
#undef ISSUE

    // write partial: Ohat = O/l (bf16), l (f32)
    const int slot = bh * 40 + POFF[p] + c;
    #pragma unroll
    for (int mi = 0; mi < 2; ++mi)
        #pragma unroll
        for (int r = 0; r < 4; ++r) {
            const int idx = mi * 4 + r;
            float ls = lp[idx];
            ls += __shfl_xor(ls, 1);
            ls += __shfl_xor(ls, 2);
            ls += __shfl_xor(ls, 4);
            ls += __shfl_xor(ls, 8);
            const float inv = 1.f / ls;
            const int rloc = w * 32 + mi * 16 + rl * 4 + r;
            if (cl == 0) ML[(size_t)slot * 128 + rloc] = ls;
            #pragma unroll
            for (int di = 0; di < 4; ++di)
                Opart[(size_t)slot * 8192 + rloc * 64 + di * 16 + cl] =
                    f2bf(o[mi][di][r] * inv);
        }
}

// ---------------------------------------------------------------------------
// Kernel 2b: combine partials -> YH [b][t][c] bf16. weights = l_c / sum l_c.
// ---------------------------------------------------------------------------
__global__ __launch_bounds__(256)
void attn_combine(const u16* __restrict__ Opart, const float* __restrict__ ML,
                  u16* __restrict__ YH)
{
    const int wg = blockIdx.x;
    const int bh = wg & 31;
    const int p  = wg >> 5;
    const int b = bh >> 3, h = bh & 7;
    const int nc = CPER[p >> 1];
    const int sb = bh * 40 + POFF[p];

    const int t = threadIdx.x;
    const int rloc = t >> 1;
    const int dh = (t & 1) * 32;

    float lc[4], L = 0.f;
    for (int c = 0; c < nc; ++c) {
        lc[c] = ML[(size_t)(sb + c) * 128 + rloc];
        L += lc[c];
    }
    const float invL = 1.f / L;
    float wgt[4];
    for (int c = 0; c < nc; ++c) wgt[c] = lc[c] * invL;

    f4v a[8] = {};
    for (int c = 0; c < nc; ++c) {
        const float wv = wgt[c];
        #pragma unroll
        for (int u = 0; u < 4; ++u) {
            s8v vv = *reinterpret_cast<const s8v*>(
                &Opart[(size_t)(sb + c) * 8192 + rloc * 64 + dh + u * 8]);
            #pragma unroll
            for (int e = 0; e < 4; ++e) a[u * 2][e]     += wv * bf2f((u16)vv[e]);
            #pragma unroll
            for (int e = 0; e < 4; ++e) a[u * 2 + 1][e] += wv * bf2f((u16)vv[e + 4]);
        }
    }

    const size_t ybase = ((size_t)b * 2048 + p * 128 + rloc) * 512 + h * 64 + dh;
    #pragma unroll
    for (int u = 0; u < 4; ++u) {
        s8v ov;
        #pragma unroll
        for (int e = 0; e < 4; ++e) ov[e]     = (short)f2bf(a[u * 2][e]);
        #pragma unroll
        for (int e = 0; e < 4; ++e) ov[e + 4] = (short)f2bf(a[u * 2 + 1][e]);
        *reinterpret_cast<s8v*>(YH + ybase + u * 8) = ov;
    }
}

// ---------------------------------------------------------------------------
// Kernel 3: output projection (transposed): C'[c][tok] = Wp^T . Y^T.
// Swizzled Wp tile; XCD-chunked map; T14 pipeline as in qkv_proj.
// ---------------------------------------------------------------------------
__global__ __launch_bounds__(256)
void out_proj(const u16* __restrict__ YH, const float* __restrict__ Wp,
              const float* __restrict__ bp, float* __restrict__ out)
{
    __shared__ __align__(16) u16 Al[128 * 64];   // Wp^T tile, swizzled
    __shared__ u16 Bl[128][40];                  // Y tile (linear b128 write)

    const int bid = blockIdx.x;
    const int x = bid & 7, i = bid >> 3;         // 256 blocks
    const int mt = x + 8 * (i >> 2);
    const int ct = i & 3;
    const int c0 = ct << 7, m0 = mt << 7;

    const int tid = threadIdx.x, lane = tid & 63, w = tid >> 6;
    const int wr = (w >> 1) * 64, wc = (w & 1) * 64;
    const int cl = lane & 15, rl = lane >> 4;

    f4v acc[4][4] = {};
    f4v sa[4];
    s8v sy[2];

    const int lk = tid >> 3;
    const int lg = (tid & 7) * 16;
    const int br = tid >> 2;
    const int bq4 = (tid & 3) * 8;

#define OP_LOAD(k0_) do {                                                    \
        const float* gA = Wp + (size_t)((k0_) + lk) * 512 + c0 + lg;         \
        _Pragma("unroll")                                                    \
        for (int u = 0; u < 4; ++u)                                          \
            sa[u] = *reinterpret_cast<const f4v*>(gA + u * 4);               \
        _Pragma("unroll")                                                    \
        for (int it = 0; it < 2; ++it)                                       \
            sy[it] = *reinterpret_cast<const s8v*>(                          \
                YH + (size_t)(m0 + br + it * 64) * 512 + (k0_) + bq4);       \
    } while (0)

    OP_LOAD(0);

    for (int k0 = 0; k0 < 512; k0 += 32) {
        #pragma unroll
        for (int u = 0; u < 4; ++u) {
            unsigned a0 = cvtpk(sa[u][0], sa[u][1]);
            unsigned a1 = cvtpk(sa[u][2], sa[u][3]);
            *(u16*)((char*)Al + swb(lg + u * 4 + 0, lk * 2)) = (u16)a0;
            *(u16*)((char*)Al + swb(lg + u * 4 + 1, lk * 2)) = (u16)(a0 >> 16);
            *(u16*)((char*)Al + swb(lg + u * 4 + 2, lk * 2)) = (u16)a1;
            *(u16*)((char*)Al + swb(lg + u * 4 + 3, lk * 2)) = (u16)(a1 >> 16);
        }
        #pragma unroll
        for (int it = 0; it < 2; ++it)
            *reinterpret_cast<s8v*>(&Bl[br + it * 64][bq4]) = sy[it];
        __syncthreads();
        if (k0 + 32 < 512) OP_LOAD(k0 + 32);

        s8v af[4], bfr[4];
        #pragma unroll
        for (int mi = 0; mi < 4; ++mi)
            af[mi] = *(const s8v*)((const char*)Al + swb(wr + mi * 16 + cl, rl * 16));
        #pragma unroll
        for (int ni = 0; ni < 4; ++ni)
            bfr[ni] = *reinterpret_cast<const s8v*>(&Bl[wc + ni * 16 + cl][rl * 8]);
        #pragma unroll
        for (int mi = 0; mi < 4; ++mi)
            #pragma unroll
            for (int ni = 0; ni < 4; ++ni)
                acc[mi][ni] = MFMA(af[mi], bfr[ni], acc[mi][ni]);
        __syncthreads();
    }
#undef OP_LOAD

    #pragma unroll
    for (int mi = 0; mi < 4; ++mi)
        #pragma unroll
        for (int r = 0; r < 4; ++r) {
            const int c = c0 + wr + mi * 16 + rl * 4 + r;   // D row = cout
            const float bv = bp[c];
            #pragma unroll
            for (int ni = 0; ni < 4; ++ni) {
                const int tok = m0 + wc + ni * 16 + cl;     // D col = token
                const int bb = tok >> 11, t = tok & 2047;
                const int vv = t >> 8, hw = t & 255;
                out[(size_t)(vv * 4 + bb) * 131072 + (size_t)c * 256 + hw] =
                    acc[mi][ni][r] + bv;
            }
        }
}

// ---------------------------------------------------------------------------
extern "C" void kernel_launch(void* const* d_in, const int* in_sizes, int n_in,
                              void* d_out, int out_size, void* d_ws, size_t ws_size,
                              hipStream_t stream)
{
    const float* q   = (const float*)d_in[0];
    const float* kv  = (const float*)d_in[1];
    const float* Wq  = (const float*)d_in[2];
    const float* bq  = (const float*)d_in[3];
    const float* Wkv = (const float*)d_in[4];
    const float* bkv = (const float*)d_in[5];
    const float* Wp  = (const float*)d_in[6];
    const float* bp  = (const float*)d_in[7];
    float* out = (float*)d_out;

    u16* ws = (u16*)d_ws;
    u16* QH = ws;                    // [4][8][2048][64] bf16, prescaled Q
    u16* KH = QH + 4194304;          // [4][8][2048][64]
    u16* VT = KH + 4194304;          // [4][8][64][2048]
    u16* YH = VT + 4194304;          // [4][2048][512]
    u16* Opart = YH + 4194304;       // [1280][128][64] bf16 = 20 MB
    float* ML  = (float*)(Opart + 10485760);  // [1280][128] f32 = 0.66 MB

    hipLaunchKernelGGL(qkv_proj, dim3(768), dim3(256), 0, stream,
                       q, kv, Wq, bq, Wkv, bkv, QH, KH, VT);
    hipLaunchKernelGGL(attn_part, dim3(1280), dim3(256), 0, stream,
                       QH, KH, VT, Opart, ML);
    hipLaunchKernelGGL(attn_combine, dim3(512), dim3(256), 0, stream,
                       Opart, ML, YH);
    hipLaunchKernelGGL(out_proj, dim3(256), dim3(256), 0, stream, YH, Wp, bp, out);
}